// Round 4
// baseline (375.668 us; speedup 1.0000x reference)
//
#include <hip/hip_runtime.h>
#include <math.h>

// ---------------------------------------------------------------------------
// SALAD forward, bf16-MFMA, round 4: merged stage-1 GEMM (cw1|sw1 in one
// dispatch, weight selected per col-tile) -> hT2[B][N][1024]; stage-2 GEMMs
// read respective halves via lda. GEMM inner loop unchanged (m97 structure).
// B=64, C=768, N=1024, HID=512, L=128, M=64, G=256.
// ---------------------------------------------------------------------------

#define B_SZ   64
#define C_IN   768
#define N_LOC  1024
#define HID    512
#define L_DIM  128
#define M_DIM  64
#define G_DIM  256

typedef unsigned short u16;
typedef __bf16 bf16x8 __attribute__((ext_vector_type(8)));
typedef float f32x4 __attribute__((ext_vector_type(4)));

typedef const __attribute__((address_space(1))) void* gptr_t;
typedef __attribute__((address_space(3))) void* sptr_t;

__device__ __forceinline__ void load_lds16(const void* g, void* l) {
    __builtin_amdgcn_global_load_lds((gptr_t)g, (sptr_t)l, 16, 0, 0);
}

__device__ __forceinline__ u16 f2bf(float f) {  // round-to-nearest-even
    unsigned u = __float_as_uint(f);
    u += 0x7fffu + ((u >> 16) & 1u);
    return (u16)(u >> 16);
}
__device__ __forceinline__ float bf2f(u16 h) {
    return __uint_as_float(((unsigned)h) << 16);
}

__device__ __forceinline__ float waveReduceSum(float v) {
#pragma unroll
    for (int off = 32; off > 0; off >>= 1) v += __shfl_xor(v, off, 64);
    return v;
}

// ---------------------------------------------------------------------------
// fp32 -> bf16 elementwise convert (weights). n % 4 == 0.
// ---------------------------------------------------------------------------
__global__ __launch_bounds__(256) void convert_bf16_k(const float* __restrict__ in,
                                                      u16* __restrict__ out, int n) {
    int i = (blockIdx.x * 256 + threadIdx.x) * 4;
    if (i >= n) return;
    float4 v = *(const float4*)(in + i);
    ushort4 o = make_ushort4(f2bf(v.x), f2bf(v.y), f2bf(v.z), f2bf(v.w));
    *(ushort4*)(out + i) = o;
}

// ---------------------------------------------------------------------------
// x [B][C][N] fp32 -> xT [B][N][C] bf16.  64x64 tiles, float4 loads,
// ushort4 coalesced stores. grid = (N/64, C/64, B), block 256.
// ---------------------------------------------------------------------------
__global__ __launch_bounds__(256) void transpose_x(const float* __restrict__ x,
                                                   u16* __restrict__ xT) {
    __shared__ float tile[64][65];
    const int n0 = blockIdx.x * 64;
    const int c0 = blockIdx.y * 64;
    const size_t b = blockIdx.z;
    const float* xb = x + b * (size_t)(C_IN * N_LOC);
    u16* xtb = xT + b * (size_t)(N_LOC * C_IN);
    const int tid = threadIdx.x;

    const int jn = (tid & 15) * 4;
    const int cr = tid >> 4;
#pragma unroll
    for (int r = 0; r < 4; ++r) {
        int c = cr + r * 16;
        float4 v = *(const float4*)(xb + (size_t)(c0 + c) * N_LOC + n0 + jn);
        tile[c][jn + 0] = v.x;
        tile[c][jn + 1] = v.y;
        tile[c][jn + 2] = v.z;
        tile[c][jn + 3] = v.w;
    }
    __syncthreads();
    const int c4 = (tid & 15) * 4;
#pragma unroll
    for (int r = 0; r < 4; ++r) {
        int n = (tid >> 4) + r * 16;
        ushort4 o = make_ushort4(f2bf(tile[c4 + 0][n]), f2bf(tile[c4 + 1][n]),
                                 f2bf(tile[c4 + 2][n]), f2bf(tile[c4 + 3][n]));
        *(ushort4*)(xtb + (size_t)(n0 + n) * C_IN + c0 + c4) = o;
    }
}

// ---------------------------------------------------------------------------
// bf16 MFMA GEMM with per-col-tile weight/bias source selection.
// Out[b][r][c0+c] = act( sum_k A[b][r][k] * Wsel[cw+c][k] + bsel[cw+c] )
// where (Wsel,bsel,cw) = c0 < wsplit ? (W0,b0,c0) : (W1,b1,c0-wsplit).
// A row stride lda, Out row stride ldo. Tile 128 x BN, BK=64, 4 waves (2x2).
// grid = (N_LOC/128, Stotal/BN, B).
// ---------------------------------------------------------------------------
template <int BN, bool RELU>
__global__ __launch_bounds__(256) void gemm_bf16(const u16* __restrict__ A, int lda,
                                                 const u16* __restrict__ W0,
                                                 const u16* __restrict__ W1, int wsplit,
                                                 const float* __restrict__ b0,
                                                 const float* __restrict__ b1,
                                                 u16* __restrict__ Out, int ldo, int K) {
    constexpr int WN = BN / 2;
    constexpr int FN = WN / 16;
    __shared__ __align__(16) u16 As[128 * 64];
    __shared__ __align__(16) u16 Bs[BN * 64];
    const int tid = threadIdx.x;
    const int lane = tid & 63;
    const int wv = tid >> 6;
    const int wr = wv >> 1;
    const int wc = wv & 1;
    const int r0 = blockIdx.x * 128;
    const int c0 = blockIdx.y * BN;
    const size_t bb = blockIdx.z;

    const bool sel = c0 >= wsplit;
    const int cw = sel ? c0 - wsplit : c0;
    const u16* Wb = (sel ? W1 : W0) + (size_t)cw * K;
    const float* bsrc = sel ? b1 : b0;

    const u16* Ab = A + bb * (size_t)N_LOC * lda + (size_t)r0 * lda;

    f32x4 acc[4][FN];
#pragma unroll
    for (int mi = 0; mi < 4; ++mi)
#pragma unroll
        for (int ni = 0; ni < FN; ++ni)
            acc[mi][ni] = (f32x4){0.f, 0.f, 0.f, 0.f};

    const int srow = tid >> 3;        // 0..31
    const int scol = (tid & 7) * 8;   // ushort offset in 64-wide row

    const int nk = K / 64;
    for (int kt = 0; kt < nk; ++kt) {
        const int kbase = kt * 64 + scol;
#pragma unroll
        for (int j = 0; j < 4; ++j) {
            int row = j * 32 + srow;
            load_lds16(Ab + (size_t)row * lda + kbase, &As[(size_t)(j * 256 + tid) * 8]);
        }
#pragma unroll
        for (int j = 0; j < BN / 32; ++j) {
            int row = j * 32 + srow;
            load_lds16(Wb + (size_t)row * K + kbase, &Bs[(size_t)(j * 256 + tid) * 8]);
        }
        __syncthreads();
#pragma unroll
        for (int kk = 0; kk < 2; ++kk) {
            bf16x8 av[4], bw[FN];
#pragma unroll
            for (int mi = 0; mi < 4; ++mi)
                av[mi] = *(const bf16x8*)&As[(wr * 64 + mi * 16 + (lane & 15)) * 64 +
                                             kk * 32 + (lane >> 4) * 8];
#pragma unroll
            for (int ni = 0; ni < FN; ++ni)
                bw[ni] = *(const bf16x8*)&Bs[(wc * WN + ni * 16 + (lane & 15)) * 64 +
                                             kk * 32 + (lane >> 4) * 8];
#pragma unroll
            for (int mi = 0; mi < 4; ++mi)
#pragma unroll
                for (int ni = 0; ni < FN; ++ni)
                    acc[mi][ni] = __builtin_amdgcn_mfma_f32_16x16x32_bf16(
                        av[mi], bw[ni], acc[mi][ni], 0, 0, 0);
        }
        __syncthreads();
    }

    float bv[FN];
#pragma unroll
    for (int ni = 0; ni < FN; ++ni)
        bv[ni] = bsrc[cw + wc * WN + ni * 16 + (lane & 15)];
    u16* Ob = Out + bb * (size_t)N_LOC * ldo;
#pragma unroll
    for (int mi = 0; mi < 4; ++mi) {
#pragma unroll
        for (int r = 0; r < 4; ++r) {
            int row = r0 + wr * 64 + mi * 16 + (lane >> 4) * 4 + r;
#pragma unroll
            for (int ni = 0; ni < FN; ++ni) {
                int col = c0 + wc * WN + ni * 16 + (lane & 15);
                float v = acc[mi][ni][r] + bv[ni];
                if (RELU) v = fmaxf(v, 0.f);
                Ob[(size_t)row * ldo + col] = f2bf(v);
            }
        }
    }
}

// ---------------------------------------------------------------------------
// Token MLP stage 1: hidb[b][j] = relu(t[b] . tw1[j] + tb1[j])
// grid (HID/64, B), 256 thr.
// ---------------------------------------------------------------------------
__global__ __launch_bounds__(256) void tok1_kernel(const float* __restrict__ t,
                                                   const float* __restrict__ tw1,
                                                   const float* __restrict__ tb1,
                                                   float* __restrict__ hidb) {
    __shared__ __align__(16) float tl[C_IN];
    const int b = blockIdx.y;
    const int j0 = blockIdx.x * 64;
    const int tid = threadIdx.x;
    const int lane = tid & 63;
    const int wave = tid >> 6;
    for (int i = tid; i < C_IN; i += 256) tl[i] = t[(size_t)b * C_IN + i];
    __syncthreads();
    for (int j = wave; j < 64; j += 4) {
        const int row = j0 + j;
        const float4* wr = (const float4*)(tw1 + (size_t)row * C_IN);
        const float4* tr = (const float4*)tl;
        float s = 0.f;
#pragma unroll
        for (int q = 0; q < 3; ++q) {
            float4 wv = wr[lane + 64 * q];
            float4 tv = tr[lane + 64 * q];
            s += wv.x * tv.x + wv.y * tv.y + wv.z * tv.z + wv.w * tv.w;
        }
        s = waveReduceSum(s);
        if (lane == 0) hidb[(size_t)b * HID + row] = fmaxf(s + tb1[row], 0.f);
    }
}

// ---------------------------------------------------------------------------
// Token MLP stage 2: tok[b][g] = hidb[b] . tw2[g] + tb2[g]
// grid (G/64, B), 256 thr.
// ---------------------------------------------------------------------------
__global__ __launch_bounds__(256) void tok2_kernel(const float* __restrict__ hidb,
                                                   const float* __restrict__ tw2,
                                                   const float* __restrict__ tb2,
                                                   float* __restrict__ tok) {
    __shared__ __align__(16) float hl[HID];
    const int b = blockIdx.y;
    const int g0 = blockIdx.x * 64;
    const int tid = threadIdx.x;
    const int lane = tid & 63;
    const int wave = tid >> 6;
    for (int i = tid; i < HID; i += 256) hl[i] = hidb[(size_t)b * HID + i];
    __syncthreads();
    for (int j = wave; j < 64; j += 4) {
        const int row = g0 + j;
        const float4* wr = (const float4*)(tw2 + (size_t)row * HID);
        const float4* hr = (const float4*)hl;
        float s = 0.f;
#pragma unroll
        for (int q = 0; q < 2; ++q) {
            float4 wv = wr[lane + 64 * q];
            float4 hv = hr[lane + 64 * q];
            s += wv.x * hv.x + wv.y * hv.y + wv.z * hv.z + wv.w * hv.w;
        }
        s = waveReduceSum(s);
        if (lane == 0) tok[(size_t)b * G_DIM + row] = s + tb2[row];
    }
}

// ---------------------------------------------------------------------------
// Sinkhorn: pT [B][N][M] bf16 -> PT [B][N][M] fp32.
// One block (1024 thr) per batch; p staged in LDS as sp[m][n] (128 KB).
// ---------------------------------------------------------------------------
__global__ __launch_bounds__(1024) void sinkhorn_kernel(const u16* __restrict__ pT,
                                                        const float* __restrict__ dust,
                                                        float* __restrict__ PT) {
    __shared__ u16 sp[M_DIM][N_LOC];   // 131072 B
    __shared__ float u[M_DIM + 1];
    __shared__ float v[N_LOC];
    const int b = blockIdx.x;
    const int t = threadIdx.x;
    const int lane = t & 63;
    const int wave = t >> 6;
    const float alpha = dust[0];
    const float norm = -__logf(1088.f);
    const float logmu_main = norm;
    const float logmu_last = __logf(960.f) + norm;
    const float lognu = norm;

    const uint4* prow = (const uint4*)(pT + ((size_t)b * N_LOC + t) * M_DIM);
#pragma unroll
    for (int q = 0; q < 8; ++q) {
        uint4 ch = prow[q];
        sp[q * 8 + 0][t] = (u16)(ch.x);
        sp[q * 8 + 1][t] = (u16)(ch.x >> 16);
        sp[q * 8 + 2][t] = (u16)(ch.y);
        sp[q * 8 + 3][t] = (u16)(ch.y >> 16);
        sp[q * 8 + 4][t] = (u16)(ch.z);
        sp[q * 8 + 5][t] = (u16)(ch.z >> 16);
        sp[q * 8 + 6][t] = (u16)(ch.w);
        sp[q * 8 + 7][t] = (u16)(ch.w >> 16);
    }
    v[t] = 0.f;
    if (t < M_DIM + 1) u[t] = 0.f;
    __syncthreads();

    for (int it = 0; it < 3; ++it) {
        for (int m = wave; m < M_DIM + 1; m += 16) {
            float s = 0.f;
            if (m < M_DIM) {
#pragma unroll
                for (int q = 0; q < 16; ++q) {
                    int c = lane + 64 * q;
                    s += __expf(bf2f(sp[m][c]) + v[c]);
                }
            } else {
#pragma unroll
                for (int q = 0; q < 16; ++q) {
                    int c = lane + 64 * q;
                    s += __expf(alpha + v[c]);
                }
            }
            s = waveReduceSum(s);
            if (lane == 0) u[m] = ((m < M_DIM) ? logmu_main : logmu_last) - __logf(s);
        }
        __syncthreads();
        float s = 0.f;
#pragma unroll 8
        for (int m = 0; m < M_DIM; ++m) s += __expf(bf2f(sp[m][t]) + u[m]);
        s += __expf(alpha + u[M_DIM]);
        v[t] = lognu - __logf(s);
        __syncthreads();
    }

    const float vt = v[t];
    float* Prow = PT + ((size_t)b * N_LOC + t) * M_DIM;
#pragma unroll
    for (int m4 = 0; m4 < M_DIM; m4 += 4) {
        float4 o;
        o.x = __expf(bf2f(sp[m4 + 0][t]) + u[m4 + 0] + vt - norm);
        o.y = __expf(bf2f(sp[m4 + 1][t]) + u[m4 + 1] + vt - norm);
        o.z = __expf(bf2f(sp[m4 + 2][t]) + u[m4 + 2] + vt - norm);
        o.w = __expf(bf2f(sp[m4 + 3][t]) + u[m4 + 3] + vt - norm);
        *(float4*)(Prow + m4) = o;
    }
}

// ---------------------------------------------------------------------------
// agg[b,l,m] = sum_n fT[b,n,l] * PT[b,n,m].
// grid (L/32, B), 256 thr; block tile 32l x 64m; thread 2l x 4m.
// ---------------------------------------------------------------------------
__global__ __launch_bounds__(256) void agg_kernel(const u16* __restrict__ fT,
                                                  const float* __restrict__ PT,
                                                  float* __restrict__ agg) {
    __shared__ float Fs[64][36];
    __shared__ float Ps[64][68];
    const int b = blockIdx.y;
    const int l0 = blockIdx.x * 32;
    const int tid = threadIdx.x;
    const u16* fb = fT + (size_t)b * N_LOC * L_DIM;
    const float* Pb = PT + (size_t)b * N_LOC * M_DIM;

    const int sn = tid >> 2;
    const int flc = (tid & 3) * 8;
    const int pmc = (tid & 3) * 16;
    const int tl = (tid >> 4) * 2;
    const int tm = (tid & 15) * 4;

    float acc[2][4] = {};

    for (int n0 = 0; n0 < N_LOC; n0 += 64) {
        __syncthreads();
        {
            uint4 ld = *(const uint4*)(fb + (size_t)(n0 + sn) * L_DIM + l0 + flc);
            Fs[sn][flc + 0] = bf2f((u16)(ld.x));
            Fs[sn][flc + 1] = bf2f((u16)(ld.x >> 16));
            Fs[sn][flc + 2] = bf2f((u16)(ld.y));
            Fs[sn][flc + 3] = bf2f((u16)(ld.y >> 16));
            Fs[sn][flc + 4] = bf2f((u16)(ld.z));
            Fs[sn][flc + 5] = bf2f((u16)(ld.z >> 16));
            Fs[sn][flc + 6] = bf2f((u16)(ld.w));
            Fs[sn][flc + 7] = bf2f((u16)(ld.w >> 16));
        }
#pragma unroll
        for (int i = 0; i < 4; ++i) {
            float4 vv = *(const float4*)(Pb + (size_t)(n0 + sn) * M_DIM + pmc + 4 * i);
            *(float4*)&Ps[sn][pmc + 4 * i] = vv;
        }
        __syncthreads();
#pragma unroll 8
        for (int nn = 0; nn < 64; ++nn) {
            float a0 = Fs[nn][tl];
            float a1 = Fs[nn][tl + 1];
            float4 p4 = *(const float4*)&Ps[nn][tm];
            acc[0][0] = fmaf(a0, p4.x, acc[0][0]);
            acc[0][1] = fmaf(a0, p4.y, acc[0][1]);
            acc[0][2] = fmaf(a0, p4.z, acc[0][2]);
            acc[0][3] = fmaf(a0, p4.w, acc[0][3]);
            acc[1][0] = fmaf(a1, p4.x, acc[1][0]);
            acc[1][1] = fmaf(a1, p4.y, acc[1][1]);
            acc[1][2] = fmaf(a1, p4.z, acc[1][2]);
            acc[1][3] = fmaf(a1, p4.w, acc[1][3]);
        }
    }

#pragma unroll
    for (int i = 0; i < 2; ++i) {
        float* dst = agg + ((size_t)b * L_DIM + l0 + tl + i) * M_DIM + tm;
        *(float4*)dst = make_float4(acc[i][0], acc[i][1], acc[i][2], acc[i][3]);
    }
}

// ---------------------------------------------------------------------------
// Final normalization cascade.
// ---------------------------------------------------------------------------
__global__ __launch_bounds__(256) void final_kernel(const float* __restrict__ agg,
                                                    const float* __restrict__ tok,
                                                    float* __restrict__ out) {
    __shared__ __align__(16) float ag[L_DIM * M_DIM];
    __shared__ float rm[M_DIM];
    __shared__ float red[4];
    __shared__ float tk[G_DIM];
    const int b = blockIdx.x;
    const int tid = threadIdx.x;
    const int lane = tid & 63;
    const int wave = tid >> 6;
    const float EPS = 1e-12f;

    const float4* ab = (const float4*)(agg + (size_t)b * L_DIM * M_DIM);
    for (int e4 = tid; e4 < L_DIM * M_DIM / 4; e4 += 256) ((float4*)ag)[e4] = ab[e4];
    tk[tid] = tok[(size_t)b * G_DIM + tid];
    __syncthreads();

    if (tid < M_DIM) {
        float ss = 0.f;
#pragma unroll 8
        for (int l = 0; l < L_DIM; ++l) {
            float x = ag[l * M_DIM + tid];
            ss = fmaf(x, x, ss);
        }
        rm[tid] = 1.f / fmaxf(sqrtf(ss), EPS);
    }
    const float tv = tk[tid];
    float ssl = tv * tv;
    ssl = waveReduceSum(ssl);
    if (lane == 0) red[wave] = ssl;
    __syncthreads();
    const float stok = red[0] + red[1] + red[2] + red[3];
    const float rt = 1.f / fmaxf(sqrtf(stok), EPS);
    const float tn = tv * rt;

    float gs = tn * tn;
    for (int e = tid; e < L_DIM * M_DIM; e += 256) {
        float x = ag[e] * rm[e & (M_DIM - 1)];
        gs = fmaf(x, x, gs);
    }
    __syncthreads();
    gs = waveReduceSum(gs);
    if (lane == 0) red[wave] = gs;
    __syncthreads();
    const float G = red[0] + red[1] + red[2] + red[3];
    const float rg = 1.f / fmaxf(sqrtf(G), EPS);

    float* ob = out + (size_t)b * (G_DIM + L_DIM * M_DIM);
    ob[tid] = tn * rg;
    for (int e = tid; e < L_DIM * M_DIM; e += 256)
        ob[G_DIM + e] = ag[e] * rm[e & (M_DIM - 1)] * rg;
}

// ---------------------------------------------------------------------------
extern "C" void kernel_launch(void* const* d_in, const int* in_sizes, int n_in,
                              void* d_out, int out_size, void* d_ws, size_t ws_size,
                              hipStream_t stream) {
    const float* x    = (const float*)d_in[0];
    const float* t    = (const float*)d_in[1];
    const float* tw1  = (const float*)d_in[2];
    const float* tb1  = (const float*)d_in[3];
    const float* tw2  = (const float*)d_in[4];
    const float* tb2  = (const float*)d_in[5];
    const float* cw1  = (const float*)d_in[6];
    const float* cb1  = (const float*)d_in[7];
    const float* cw2  = (const float*)d_in[8];
    const float* cb2  = (const float*)d_in[9];
    const float* sw1  = (const float*)d_in[10];
    const float* sb1  = (const float*)d_in[11];
    const float* sw2  = (const float*)d_in[12];
    const float* sb2  = (const float*)d_in[13];
    const float* dust = (const float*)d_in[14];
    float* out = (float*)d_out;

    char* ws = (char*)d_ws;
    u16* xT    = (u16*)(ws);                         // 100,663,296
    u16* hT2   = (u16*)(ws + 100663296ull);          // 134,217,728  [B][N][1024]
    u16* fT    = (u16*)(ws + 234881024ull);          //  16,777,216
    u16* pT    = (u16*)(ws + 251658240ull);          //   8,388,608
    u16* cw1b  = (u16*)(ws + 260046848ull);          //     786,432
    u16* sw1b  = (u16*)(ws + 260833280ull);          //     786,432
    u16* cw2b  = (u16*)(ws + 261619712ull);          //     131,072
    u16* sw2b  = (u16*)(ws + 261750784ull);          //      65,536
    float* hidb = (float*)(ws + 261816320ull);       //     131,072
    // reuse of dead xT region after stage-1:
    float* PT     = (float*)(ws);                    //  16,777,216
    float* tokbuf = (float*)(ws + 20971520ull);      //      65,536
    float* aggbuf = (float*)(ws + 25165824ull);      //   2,097,152

    convert_bf16_k<<<(HID * C_IN / 4 + 255) / 256, 256, 0, stream>>>(cw1, cw1b, HID * C_IN);
    convert_bf16_k<<<(HID * C_IN / 4 + 255) / 256, 256, 0, stream>>>(sw1, sw1b, HID * C_IN);
    convert_bf16_k<<<(L_DIM * HID / 4 + 255) / 256, 256, 0, stream>>>(cw2, cw2b, L_DIM * HID);
    convert_bf16_k<<<(M_DIM * HID / 4 + 255) / 256, 256, 0, stream>>>(sw2, sw2b, M_DIM * HID);
    transpose_x<<<dim3(N_LOC / 64, C_IN / 64, B_SZ), 256, 0, stream>>>(x, xT);

    // merged stage-1: cols 0..511 = relu(x.cw1^T+cb1), 512..1023 = relu(x.sw1^T+sb1)
    gemm_bf16<128, true><<<dim3(8, 8, B_SZ), 256, 0, stream>>>(
        xT, C_IN, cw1b, sw1b, 512, cb1, sb1, hT2, 1024, C_IN);
    // stage-2 f: reads h half (cols 0..511)
    gemm_bf16<128, false><<<dim3(8, 1, B_SZ), 256, 0, stream>>>(
        hT2, 1024, cw2b, cw2b, 1 << 30, cb2, cb2, fT, L_DIM, HID);
    // stage-2 p: reads s half (cols 512..1023)
    gemm_bf16<64, false><<<dim3(8, 1, B_SZ), 256, 0, stream>>>(
        hT2 + 512, 1024, sw2b, sw2b, 1 << 30, sb2, sb2, pT, M_DIM, HID);

    tok1_kernel<<<dim3(HID / 64, B_SZ), 256, 0, stream>>>(t, tw1, tb1, hidb);
    tok2_kernel<<<dim3(G_DIM / 64, B_SZ), 256, 0, stream>>>(hidb, tw2, tb2, tokbuf);

    sinkhorn_kernel<<<B_SZ, 1024, 0, stream>>>(pT, dust, PT);
    agg_kernel<<<dim3(L_DIM / 32, B_SZ), 256, 0, stream>>>(fT, PT, aggbuf);
    final_kernel<<<B_SZ, 256, 0, stream>>>(aggbuf, tokbuf, out);
}

// Round 5
// 361.766 us; speedup vs baseline: 1.0384x; 1.0384x over previous
//
#include <hip/hip_runtime.h>
#include <math.h>

// ---------------------------------------------------------------------------
// SALAD forward, round 5: stage-1 GEMM rebuilt as 256x256xBK64 deep-pipelined
// MFMA kernel (counted vmcnt across raw barriers, XOR-swizzled LDS, setprio,
// XCD-bijective block remap). Stage-2 GEMMs back on compact h/s buffers.
// Layouts: xT[B][N][C], hbuf[B][N][512], sbuf[B][N][512], fT[B][N][128],
// pT[B][N][64] (bf16); PT[B][N][64] fp32.
// B=64, C=768, N=1024, HID=512, L=128, M=64, G=256.
// ---------------------------------------------------------------------------

#define B_SZ   64
#define C_IN   768
#define N_LOC  1024
#define HID    512
#define L_DIM  128
#define M_DIM  64
#define G_DIM  256

typedef unsigned short u16;
typedef __bf16 bf16x8 __attribute__((ext_vector_type(8)));
typedef float f32x4 __attribute__((ext_vector_type(4)));

typedef const __attribute__((address_space(1))) void* gptr_t;
typedef __attribute__((address_space(3))) void* sptr_t;

__device__ __forceinline__ void load_lds16(const void* g, void* l) {
    __builtin_amdgcn_global_load_lds((gptr_t)g, (sptr_t)l, 16, 0, 0);
}

__device__ __forceinline__ u16 f2bf(float f) {  // round-to-nearest-even
    unsigned u = __float_as_uint(f);
    u += 0x7fffu + ((u >> 16) & 1u);
    return (u16)(u >> 16);
}
__device__ __forceinline__ float bf2f(u16 h) {
    return __uint_as_float(((unsigned)h) << 16);
}

__device__ __forceinline__ float waveReduceSum(float v) {
#pragma unroll
    for (int off = 32; off > 0; off >>= 1) v += __shfl_xor(v, off, 64);
    return v;
}

// ---------------------------------------------------------------------------
// fp32 -> bf16 elementwise convert (weights). n % 4 == 0.
// ---------------------------------------------------------------------------
__global__ __launch_bounds__(256) void convert_bf16_k(const float* __restrict__ in,
                                                      u16* __restrict__ out, int n) {
    int i = (blockIdx.x * 256 + threadIdx.x) * 4;
    if (i >= n) return;
    float4 v = *(const float4*)(in + i);
    ushort4 o = make_ushort4(f2bf(v.x), f2bf(v.y), f2bf(v.z), f2bf(v.w));
    *(ushort4*)(out + i) = o;
}

// ---------------------------------------------------------------------------
// x [B][C][N] fp32 -> xT [B][N][C] bf16.  64x64 tiles via LDS.
// grid = (N/64, C/64, B), block 256.
// ---------------------------------------------------------------------------
__global__ __launch_bounds__(256) void transpose_x(const float* __restrict__ x,
                                                   u16* __restrict__ xT) {
    __shared__ float tile[64][65];
    const int n0 = blockIdx.x * 64;
    const int c0 = blockIdx.y * 64;
    const size_t b = blockIdx.z;
    const float* xb = x + b * (size_t)(C_IN * N_LOC);
    u16* xtb = xT + b * (size_t)(N_LOC * C_IN);
    const int tid = threadIdx.x;

    const int jn = (tid & 15) * 4;
    const int cr = tid >> 4;
#pragma unroll
    for (int r = 0; r < 4; ++r) {
        int c = cr + r * 16;
        float4 v = *(const float4*)(xb + (size_t)(c0 + c) * N_LOC + n0 + jn);
        tile[c][jn + 0] = v.x;
        tile[c][jn + 1] = v.y;
        tile[c][jn + 2] = v.z;
        tile[c][jn + 3] = v.w;
    }
    __syncthreads();
    const int c4 = (tid & 15) * 4;
#pragma unroll
    for (int r = 0; r < 4; ++r) {
        int n = (tid >> 4) + r * 16;
        ushort4 o = make_ushort4(f2bf(tile[c4 + 0][n]), f2bf(tile[c4 + 1][n]),
                                 f2bf(tile[c4 + 2][n]), f2bf(tile[c4 + 3][n]));
        *(ushort4*)(xtb + (size_t)(n0 + n) * C_IN + c0 + c4) = o;
    }
}

// ---------------------------------------------------------------------------
// Deep-pipelined 256x256 bf16 MFMA GEMM, dual weight/output select.
//   tile out cols c0: c0<512 -> (W0,b0,O0,col=c0) else (W1,b1,O1,col=c0-512)
// 512 threads = 8 waves (2 M x 4 N); per-wave 128x64 out; acc[8][4] f32x4.
// LDS: 2 buffers x (A 256x64 + B 256x64) bf16 = 128 KiB, XOR-swizzled
// (slot = cc ^ (row&7); global source pre-swizzled, gload_lds dest linear).
// Loop: STAGE(kt+1) ; vmcnt(8) ; barrier ; ds_read+MFMA(setprio) ; barrier.
// Prefetch loads remain in flight across barriers (T4). grid (4,4,B).
// ---------------------------------------------------------------------------
template <bool RELU>
__global__ __launch_bounds__(512, 2) void gemm256_dual(
        const u16* __restrict__ A, int lda,
        const u16* __restrict__ W0, const u16* __restrict__ W1,
        const float* __restrict__ b0, const float* __restrict__ b1,
        u16* __restrict__ O0, u16* __restrict__ O1, int ldo, int K) {
    __shared__ __align__(16) u16 As[2][256 * 64];
    __shared__ __align__(16) u16 Bs[2][256 * 64];
    const int tid = threadIdx.x;
    const int lane = tid & 63;
    const int wid = tid >> 6;
    const int wr = wid >> 2;   // 0..1
    const int wc = wid & 3;    // 0..3

    // XCD-bijective remap: nwg = 4*4*64 = 1024, 1024 % 8 == 0.
    const int id = blockIdx.x + 4 * blockIdx.y + 16 * blockIdx.z;
    const int nid = (id & 7) * 128 + (id >> 3);
    const int bx = nid & 3;
    const int by = (nid >> 2) & 3;
    const int bz = nid >> 4;
    const int r0 = bx * 256;
    const int c0 = by * 256;

    const bool sel = (c0 >= 512);
    const u16* Wt = sel ? W1 : W0;
    const float* bt = sel ? b1 : b0;
    u16* Ot = sel ? O1 : O0;
    const int cb = sel ? (c0 - 512) : c0;   // 0 or 256 within target

    const u16* Ab = A + (size_t)bz * N_LOC * lda + (size_t)r0 * lda;
    const u16* Wb = Wt + (size_t)cb * K;

    f32x4 acc[8][4];
#pragma unroll
    for (int mi = 0; mi < 8; ++mi)
#pragma unroll
        for (int ni = 0; ni < 4; ++ni)
            acc[mi][ni] = (f32x4){0.f, 0.f, 0.f, 0.f};

    const int nk = K / 64;

#define STAGE(db, kt)                                                          \
    do {                                                                       \
        const int kb_ = (kt) * 64;                                             \
        _Pragma("unroll")                                                      \
        for (int j = 0; j < 4; ++j) {                                          \
            int q = j * 512 + tid;                                             \
            int row = q >> 3;                                                  \
            int s = (q & 7) ^ (row & 7);  /* inverse-swizzled global chunk */  \
            load_lds16(Ab + (size_t)row * lda + kb_ + s * 8,                   \
                       &As[db][(size_t)q * 8]);                                \
        }                                                                      \
        _Pragma("unroll")                                                      \
        for (int j = 0; j < 4; ++j) {                                          \
            int q = j * 512 + tid;                                             \
            int row = q >> 3;                                                  \
            int s = (q & 7) ^ (row & 7);                                       \
            load_lds16(Wb + (size_t)row * K + kb_ + s * 8,                     \
                       &Bs[db][(size_t)q * 8]);                                \
        }                                                                      \
    } while (0)

    STAGE(0, 0);
    for (int kt = 0; kt < nk; ++kt) {
        const int db = kt & 1;
        if (kt + 1 < nk) {
            STAGE(db ^ 1, kt + 1);
            // tile kt's 8 loads are the oldest; 8 newer stay in flight
            asm volatile("s_waitcnt vmcnt(8)" ::: "memory");
        } else {
            asm volatile("s_waitcnt vmcnt(0)" ::: "memory");
        }
        __builtin_amdgcn_s_barrier();          // all waves see tile kt staged
        __builtin_amdgcn_sched_barrier(0);
#pragma unroll
        for (int kk = 0; kk < 2; ++kk) {
            bf16x8 av[8], bw[4];
            const int slot = ((kk * 4 + (lane >> 4)) ^ (lane & 7)) * 8;
#pragma unroll
            for (int mi = 0; mi < 8; ++mi)
                av[mi] = *(const bf16x8*)
                    &As[db][(wr * 128 + mi * 16 + (lane & 15)) * 64 + slot];
#pragma unroll
            for (int ni = 0; ni < 4; ++ni)
                bw[ni] = *(const bf16x8*)
                    &Bs[db][(wc * 64 + ni * 16 + (lane & 15)) * 64 + slot];
            __builtin_amdgcn_s_setprio(1);
#pragma unroll
            for (int mi = 0; mi < 8; ++mi)
#pragma unroll
                for (int ni = 0; ni < 4; ++ni)
                    acc[mi][ni] = __builtin_amdgcn_mfma_f32_16x16x32_bf16(
                        av[mi], bw[ni], acc[mi][ni], 0, 0, 0);
            __builtin_amdgcn_s_setprio(0);
        }
        __builtin_amdgcn_sched_barrier(0);
        __builtin_amdgcn_s_barrier();          // reads done before re-stage
    }
#undef STAGE

    float bv[4];
#pragma unroll
    for (int ni = 0; ni < 4; ++ni)
        bv[ni] = bt[cb + wc * 64 + ni * 16 + (lane & 15)];
    u16* Ob = Ot + (size_t)bz * N_LOC * ldo;
#pragma unroll
    for (int mi = 0; mi < 8; ++mi) {
#pragma unroll
        for (int r = 0; r < 4; ++r) {
            int row = r0 + wr * 128 + mi * 16 + (lane >> 4) * 4 + r;
#pragma unroll
            for (int ni = 0; ni < 4; ++ni) {
                int col = cb + wc * 64 + ni * 16 + (lane & 15);
                float v = acc[mi][ni][r] + bv[ni];
                if (RELU) v = fmaxf(v, 0.f);
                Ob[(size_t)row * ldo + col] = f2bf(v);
            }
        }
    }
}

// ---------------------------------------------------------------------------
// m97-style 128xBN MFMA GEMM (stage-2). A row stride lda, Out stride ldo.
// grid = (N_LOC/128, S/BN, B), 256 threads (2x2 waves).
// ---------------------------------------------------------------------------
template <int BN, bool RELU>
__global__ __launch_bounds__(256) void gemm_bf16(const u16* __restrict__ A, int lda,
                                                 const u16* __restrict__ W,
                                                 const float* __restrict__ bias,
                                                 u16* __restrict__ Out, int ldo, int K) {
    constexpr int WN = BN / 2;
    constexpr int FN = WN / 16;
    __shared__ __align__(16) u16 As[128 * 64];
    __shared__ __align__(16) u16 Bs[BN * 64];
    const int tid = threadIdx.x;
    const int lane = tid & 63;
    const int wv = tid >> 6;
    const int wr = wv >> 1;
    const int wc = wv & 1;
    const int r0 = blockIdx.x * 128;
    const int c0 = blockIdx.y * BN;
    const size_t bb = blockIdx.z;
    const u16* Ab = A + bb * (size_t)N_LOC * lda + (size_t)r0 * lda;
    const u16* Wb = W + (size_t)c0 * K;

    f32x4 acc[4][FN];
#pragma unroll
    for (int mi = 0; mi < 4; ++mi)
#pragma unroll
        for (int ni = 0; ni < FN; ++ni)
            acc[mi][ni] = (f32x4){0.f, 0.f, 0.f, 0.f};

    const int srow = tid >> 3;
    const int scol = (tid & 7) * 8;

    const int nk = K / 64;
    for (int kt = 0; kt < nk; ++kt) {
        const int kbase = kt * 64 + scol;
#pragma unroll
        for (int j = 0; j < 4; ++j) {
            int row = j * 32 + srow;
            load_lds16(Ab + (size_t)row * lda + kbase, &As[(size_t)(j * 256 + tid) * 8]);
        }
#pragma unroll
        for (int j = 0; j < BN / 32; ++j) {
            int row = j * 32 + srow;
            load_lds16(Wb + (size_t)row * K + kbase, &Bs[(size_t)(j * 256 + tid) * 8]);
        }
        __syncthreads();
#pragma unroll
        for (int kk = 0; kk < 2; ++kk) {
            bf16x8 av[4], bw[FN];
#pragma unroll
            for (int mi = 0; mi < 4; ++mi)
                av[mi] = *(const bf16x8*)&As[(wr * 64 + mi * 16 + (lane & 15)) * 64 +
                                             kk * 32 + (lane >> 4) * 8];
#pragma unroll
            for (int ni = 0; ni < FN; ++ni)
                bw[ni] = *(const bf16x8*)&Bs[(wc * WN + ni * 16 + (lane & 15)) * 64 +
                                             kk * 32 + (lane >> 4) * 8];
#pragma unroll
            for (int mi = 0; mi < 4; ++mi)
#pragma unroll
                for (int ni = 0; ni < FN; ++ni)
                    acc[mi][ni] = __builtin_amdgcn_mfma_f32_16x16x32_bf16(
                        av[mi], bw[ni], acc[mi][ni], 0, 0, 0);
        }
        __syncthreads();
    }

    float bv[FN];
#pragma unroll
    for (int ni = 0; ni < FN; ++ni)
        bv[ni] = bias[c0 + wc * WN + ni * 16 + (lane & 15)];
    u16* Ob = Out + bb * (size_t)N_LOC * ldo;
#pragma unroll
    for (int mi = 0; mi < 4; ++mi) {
#pragma unroll
        for (int r = 0; r < 4; ++r) {
            int row = r0 + wr * 64 + mi * 16 + (lane >> 4) * 4 + r;
#pragma unroll
            for (int ni = 0; ni < FN; ++ni) {
                int col = c0 + wc * WN + ni * 16 + (lane & 15);
                float v = acc[mi][ni][r] + bv[ni];
                if (RELU) v = fmaxf(v, 0.f);
                Ob[(size_t)row * ldo + col] = f2bf(v);
            }
        }
    }
}

// ---------------------------------------------------------------------------
// Token MLP stage 1: hidb[b][j] = relu(t[b] . tw1[j] + tb1[j]); grid (8,B).
// ---------------------------------------------------------------------------
__global__ __launch_bounds__(256) void tok1_kernel(const float* __restrict__ t,
                                                   const float* __restrict__ tw1,
                                                   const float* __restrict__ tb1,
                                                   float* __restrict__ hidb) {
    __shared__ __align__(16) float tl[C_IN];
    const int b = blockIdx.y;
    const int j0 = blockIdx.x * 64;
    const int tid = threadIdx.x;
    const int lane = tid & 63;
    const int wave = tid >> 6;
    for (int i = tid; i < C_IN; i += 256) tl[i] = t[(size_t)b * C_IN + i];
    __syncthreads();
    for (int j = wave; j < 64; j += 4) {
        const int row = j0 + j;
        const float4* wr = (const float4*)(tw1 + (size_t)row * C_IN);
        const float4* tr = (const float4*)tl;
        float s = 0.f;
#pragma unroll
        for (int q = 0; q < 3; ++q) {
            float4 wv = wr[lane + 64 * q];
            float4 tv = tr[lane + 64 * q];
            s += wv.x * tv.x + wv.y * tv.y + wv.z * tv.z + wv.w * tv.w;
        }
        s = waveReduceSum(s);
        if (lane == 0) hidb[(size_t)b * HID + row] = fmaxf(s + tb1[row], 0.f);
    }
}

// ---------------------------------------------------------------------------
// Token MLP stage 2: tok[b][g] = hidb[b] . tw2[g] + tb2[g]; grid (4,B).
// ---------------------------------------------------------------------------
__global__ __launch_bounds__(256) void tok2_kernel(const float* __restrict__ hidb,
                                                   const float* __restrict__ tw2,
                                                   const float* __restrict__ tb2,
                                                   float* __restrict__ tok) {
    __shared__ __align__(16) float hl[HID];
    const int b = blockIdx.y;
    const int g0 = blockIdx.x * 64;
    const int tid = threadIdx.x;
    const int lane = tid & 63;
    const int wave = tid >> 6;
    for (int i = tid; i < HID; i += 256) hl[i] = hidb[(size_t)b * HID + i];
    __syncthreads();
    for (int j = wave; j < 64; j += 4) {
        const int row = g0 + j;
        const float4* wr = (const float4*)(tw2 + (size_t)row * HID);
        const float4* hr = (const float4*)hl;
        float s = 0.f;
#pragma unroll
        for (int q = 0; q < 2; ++q) {
            float4 wv = wr[lane + 64 * q];
            float4 hv = hr[lane + 64 * q];
            s += wv.x * hv.x + wv.y * hv.y + wv.z * hv.z + wv.w * hv.w;
        }
        s = waveReduceSum(s);
        if (lane == 0) tok[(size_t)b * G_DIM + row] = s + tb2[row];
    }
}

// ---------------------------------------------------------------------------
// Sinkhorn: pT [B][N][M] bf16 -> PT [B][N][M] fp32. One block/batch.
// ---------------------------------------------------------------------------
__global__ __launch_bounds__(1024) void sinkhorn_kernel(const u16* __restrict__ pT,
                                                        const float* __restrict__ dust,
                                                        float* __restrict__ PT) {
    __shared__ u16 sp[M_DIM][N_LOC];
    __shared__ float u[M_DIM + 1];
    __shared__ float v[N_LOC];
    const int b = blockIdx.x;
    const int t = threadIdx.x;
    const int lane = t & 63;
    const int wave = t >> 6;
    const float alpha = dust[0];
    const float norm = -__logf(1088.f);
    const float logmu_main = norm;
    const float logmu_last = __logf(960.f) + norm;
    const float lognu = norm;

    const uint4* prow = (const uint4*)(pT + ((size_t)b * N_LOC + t) * M_DIM);
#pragma unroll
    for (int q = 0; q < 8; ++q) {
        uint4 ch = prow[q];
        sp[q * 8 + 0][t] = (u16)(ch.x);
        sp[q * 8 + 1][t] = (u16)(ch.x >> 16);
        sp[q * 8 + 2][t] = (u16)(ch.y);
        sp[q * 8 + 3][t] = (u16)(ch.y >> 16);
        sp[q * 8 + 4][t] = (u16)(ch.z);
        sp[q * 8 + 5][t] = (u16)(ch.z >> 16);
        sp[q * 8 + 6][t] = (u16)(ch.w);
        sp[q * 8 + 7][t] = (u16)(ch.w >> 16);
    }
    v[t] = 0.f;
    if (t < M_DIM + 1) u[t] = 0.f;
    __syncthreads();

    for (int it = 0; it < 3; ++it) {
        for (int m = wave; m < M_DIM + 1; m += 16) {
            float s = 0.f;
            if (m < M_DIM) {
#pragma unroll
                for (int q = 0; q < 16; ++q) {
                    int c = lane + 64 * q;
                    s += __expf(bf2f(sp[m][c]) + v[c]);
                }
            } else {
#pragma unroll
                for (int q = 0; q < 16; ++q) {
                    int c = lane + 64 * q;
                    s += __expf(alpha + v[c]);
                }
            }
            s = waveReduceSum(s);
            if (lane == 0) u[m] = ((m < M_DIM) ? logmu_main : logmu_last) - __logf(s);
        }
        __syncthreads();
        float s = 0.f;
#pragma unroll 8
        for (int m = 0; m < M_DIM; ++m) s += __expf(bf2f(sp[m][t]) + u[m]);
        s += __expf(alpha + u[M_DIM]);
        v[t] = lognu - __logf(s);
        __syncthreads();
    }

    const float vt = v[t];
    float* Prow = PT + ((size_t)b * N_LOC + t) * M_DIM;
#pragma unroll
    for (int m4 = 0; m4 < M_DIM; m4 += 4) {
        float4 o;
        o.x = __expf(bf2f(sp[m4 + 0][t]) + u[m4 + 0] + vt - norm);
        o.y = __expf(bf2f(sp[m4 + 1][t]) + u[m4 + 1] + vt - norm);
        o.z = __expf(bf2f(sp[m4 + 2][t]) + u[m4 + 2] + vt - norm);
        o.w = __expf(bf2f(sp[m4 + 3][t]) + u[m4 + 3] + vt - norm);
        *(float4*)(Prow + m4) = o;
    }
}

// ---------------------------------------------------------------------------
// agg[b,l,m] = sum_n fT[b,n,l] * PT[b,n,m]. grid (4,B), 256 thr.
// ---------------------------------------------------------------------------
__global__ __launch_bounds__(256) void agg_kernel(const u16* __restrict__ fT,
                                                  const float* __restrict__ PT,
                                                  float* __restrict__ agg) {
    __shared__ float Fs[64][36];
    __shared__ float Ps[64][68];
    const int b = blockIdx.y;
    const int l0 = blockIdx.x * 32;
    const int tid = threadIdx.x;
    const u16* fb = fT + (size_t)b * N_LOC * L_DIM;
    const float* Pb = PT + (size_t)b * N_LOC * M_DIM;

    const int sn = tid >> 2;
    const int flc = (tid & 3) * 8;
    const int pmc = (tid & 3) * 16;
    const int tl = (tid >> 4) * 2;
    const int tm = (tid & 15) * 4;

    float acc[2][4] = {};

    for (int n0 = 0; n0 < N_LOC; n0 += 64) {
        __syncthreads();
        {
            uint4 ld = *(const uint4*)(fb + (size_t)(n0 + sn) * L_DIM + l0 + flc);
            Fs[sn][flc + 0] = bf2f((u16)(ld.x));
            Fs[sn][flc + 1] = bf2f((u16)(ld.x >> 16));
            Fs[sn][flc + 2] = bf2f((u16)(ld.y));
            Fs[sn][flc + 3] = bf2f((u16)(ld.y >> 16));
            Fs[sn][flc + 4] = bf2f((u16)(ld.z));
            Fs[sn][flc + 5] = bf2f((u16)(ld.z >> 16));
            Fs[sn][flc + 6] = bf2f((u16)(ld.w));
            Fs[sn][flc + 7] = bf2f((u16)(ld.w >> 16));
        }
#pragma unroll
        for (int i = 0; i < 4; ++i) {
            float4 vv = *(const float4*)(Pb + (size_t)(n0 + sn) * M_DIM + pmc + 4 * i);
            *(float4*)&Ps[sn][pmc + 4 * i] = vv;
        }
        __syncthreads();
#pragma unroll 8
        for (int nn = 0; nn < 64; ++nn) {
            float a0 = Fs[nn][tl];
            float a1 = Fs[nn][tl + 1];
            float4 p4 = *(const float4*)&Ps[nn][tm];
            acc[0][0] = fmaf(a0, p4.x, acc[0][0]);
            acc[0][1] = fmaf(a0, p4.y, acc[0][1]);
            acc[0][2] = fmaf(a0, p4.z, acc[0][2]);
            acc[0][3] = fmaf(a0, p4.w, acc[0][3]);
            acc[1][0] = fmaf(a1, p4.x, acc[1][0]);
            acc[1][1] = fmaf(a1, p4.y, acc[1][1]);
            acc[1][2] = fmaf(a1, p4.z, acc[1][2]);
            acc[1][3] = fmaf(a1, p4.w, acc[1][3]);
        }
    }

#pragma unroll
    for (int i = 0; i < 2; ++i) {
        float* dst = agg + ((size_t)b * L_DIM + l0 + tl + i) * M_DIM + tm;
        *(float4*)dst = make_float4(acc[i][0], acc[i][1], acc[i][2], acc[i][3]);
    }
}

// ---------------------------------------------------------------------------
// Final normalization cascade.
// ---------------------------------------------------------------------------
__global__ __launch_bounds__(256) void final_kernel(const float* __restrict__ agg,
                                                    const float* __restrict__ tok,
                                                    float* __restrict__ out) {
    __shared__ __align__(16) float ag[L_DIM * M_DIM];
    __shared__ float rm[M_DIM];
    __shared__ float red[4];
    __shared__ float tk[G_DIM];
    const int b = blockIdx.x;
    const int tid = threadIdx.x;
    const int lane = tid & 63;
    const int wave = tid >> 6;
    const float EPS = 1e-12f;

    const float4* ab = (const float4*)(agg + (size_t)b * L_DIM * M_DIM);
    for (int e4 = tid; e4 < L_DIM * M_DIM / 4; e4 += 256) ((float4*)ag)[e4] = ab[e4];
    tk[tid] = tok[(size_t)b * G_DIM + tid];
    __syncthreads();

    if (tid < M_DIM) {
        float ss = 0.f;
#pragma unroll 8
        for (int l = 0; l < L_DIM; ++l) {
            float x = ag[l * M_DIM + tid];
            ss = fmaf(x, x, ss);
        }
        rm[tid] = 1.f / fmaxf(sqrtf(ss), EPS);
    }
    const float tv = tk[tid];
    float ssl = tv * tv;
    ssl = waveReduceSum(ssl);
    if (lane == 0) red[wave] = ssl;
    __syncthreads();
    const float stok = red[0] + red[1] + red[2] + red[3];
    const float rt = 1.f / fmaxf(sqrtf(stok), EPS);
    const float tn = tv * rt;

    float gs = tn * tn;
    for (int e = tid; e < L_DIM * M_DIM; e += 256) {
        float x = ag[e] * rm[e & (M_DIM - 1)];
        gs = fmaf(x, x, gs);
    }
    __syncthreads();
    gs = waveReduceSum(gs);
    if (lane == 0) red[wave] = gs;
    __syncthreads();
    const float G = red[0] + red[1] + red[2] + red[3];
    const float rg = 1.f / fmaxf(sqrtf(G), EPS);

    float* ob = out + (size_t)b * (G_DIM + L_DIM * M_DIM);
    ob[tid] = tn * rg;
    for (int e = tid; e < L_DIM * M_DIM; e += 256)
        ob[G_DIM + e] = ag[e] * rm[e & (M_DIM - 1)] * rg;
}

// ---------------------------------------------------------------------------
extern "C" void kernel_launch(void* const* d_in, const int* in_sizes, int n_in,
                              void* d_out, int out_size, void* d_ws, size_t ws_size,
                              hipStream_t stream) {
    const float* x    = (const float*)d_in[0];
    const float* t    = (const float*)d_in[1];
    const float* tw1  = (const float*)d_in[2];
    const float* tb1  = (const float*)d_in[3];
    const float* tw2  = (const float*)d_in[4];
    const float* tb2  = (const float*)d_in[5];
    const float* cw1  = (const float*)d_in[6];
    const float* cb1  = (const float*)d_in[7];
    const float* cw2  = (const float*)d_in[8];
    const float* cb2  = (const float*)d_in[9];
    const float* sw1  = (const float*)d_in[10];
    const float* sb1  = (const float*)d_in[11];
    const float* sw2  = (const float*)d_in[12];
    const float* sb2  = (const float*)d_in[13];
    const float* dust = (const float*)d_in[14];
    float* out = (float*)d_out;

    char* ws = (char*)d_ws;
    u16* xT    = (u16*)(ws);                         // 100,663,296
    u16* hbuf  = (u16*)(ws + 100663296ull);          //  67,108,864
    u16* sbuf  = (u16*)(ws + 167772160ull);          //  67,108,864
    u16* fT    = (u16*)(ws + 234881024ull);          //  16,777,216
    u16* pT    = (u16*)(ws + 251658240ull);          //   8,388,608
    u16* cw1b  = (u16*)(ws + 260046848ull);          //     786,432
    u16* sw1b  = (u16*)(ws + 260833280ull);          //     786,432
    u16* cw2b  = (u16*)(ws + 261619712ull);          //     131,072
    u16* sw2b  = (u16*)(ws + 261750784ull);          //      65,536
    float* hidb = (float*)(ws + 261816320ull);       //     131,072
    // reuse of dead xT region after stage-1:
    float* PT     = (float*)(ws);                    //  16,777,216
    float* tokbuf = (float*)(ws + 20971520ull);      //      65,536
    float* aggbuf = (float*)(ws + 25165824ull);      //   2,097,152

    convert_bf16_k<<<(HID * C_IN / 4 + 255) / 256, 256, 0, stream>>>(cw1, cw1b, HID * C_IN);
    convert_bf16_k<<<(HID * C_IN / 4 + 255) / 256, 256, 0, stream>>>(sw1, sw1b, HID * C_IN);
    convert_bf16_k<<<(L_DIM * HID / 4 + 255) / 256, 256, 0, stream>>>(cw2, cw2b, L_DIM * HID);
    convert_bf16_k<<<(M_DIM * HID / 4 + 255) / 256, 256, 0, stream>>>(sw2, sw2b, M_DIM * HID);
    transpose_x<<<dim3(N_LOC / 64, C_IN / 64, B_SZ), 256, 0, stream>>>(x, xT);

    // merged stage-1, deep-pipelined 256x256: col-tiles 0-1 -> hbuf (cw1),
    // col-tiles 2-3 -> sbuf (sw1).
    gemm256_dual<true><<<dim3(4, 4, B_SZ), 512, 0, stream>>>(
        xT, C_IN, cw1b, sw1b, cb1, sb1, hbuf, sbuf, HID, C_IN);

    // stage-2 (compact lda=512)
    gemm_bf16<128, false><<<dim3(8, 1, B_SZ), 256, 0, stream>>>(
        hbuf, HID, cw2b, cb2, fT, L_DIM, HID);
    gemm_bf16<64, false><<<dim3(8, 1, B_SZ), 256, 0, stream>>>(
        sbuf, HID, sw2b, sb2, pT, M_DIM, HID);

    tok1_kernel<<<dim3(HID / 64, B_SZ), 256, 0, stream>>>(t, tw1, tb1, hidb);
    tok2_kernel<<<dim3(G_DIM / 64, B_SZ), 256, 0, stream>>>(hidb, tw2, tb2, tokbuf);

    sinkhorn_kernel<<<B_SZ, 1024, 0, stream>>>(pT, dust, PT);
    agg_kernel<<<dim3(L_DIM / 32, B_SZ), 256, 0, stream>>>(fT, PT, aggbuf);
    final_kernel<<<B_SZ, 256, 0, stream>>>(aggbuf, tokbuf, out);
}

// Round 6
// 352.085 us; speedup vs baseline: 1.0670x; 1.0275x over previous
//
#include <hip/hip_runtime.h>
#include <math.h>

// ---------------------------------------------------------------------------
// SALAD forward, round 6: stage-1 GEMM now uses the verified 8-phase schedule
// (T3+T4): per K-tile 4 phases, each {ds_read subtile || stage 1 half-tile ->
// barrier -> lgkmcnt(0) -> 16 MFMA quadrant -> barrier}; counted vmcnt(6)
// only at K-tile boundaries. XOR-swizzled LDS (round-5, measured 0 conflicts),
// XCD-bijective remap, setprio around MFMA. Everything else unchanged.
// B=64, C=768, N=1024, HID=512, L=128, M=64, G=256.
// ---------------------------------------------------------------------------

#define B_SZ   64
#define C_IN   768
#define N_LOC  1024
#define HID    512
#define L_DIM  128
#define M_DIM  64
#define G_DIM  256

typedef unsigned short u16;
typedef __bf16 bf16x8 __attribute__((ext_vector_type(8)));
typedef float f32x4 __attribute__((ext_vector_type(4)));

typedef const __attribute__((address_space(1))) void* gptr_t;
typedef __attribute__((address_space(3))) void* sptr_t;

__device__ __forceinline__ void load_lds16(const void* g, void* l) {
    __builtin_amdgcn_global_load_lds((gptr_t)g, (sptr_t)l, 16, 0, 0);
}

__device__ __forceinline__ u16 f2bf(float f) {  // round-to-nearest-even
    unsigned u = __float_as_uint(f);
    u += 0x7fffu + ((u >> 16) & 1u);
    return (u16)(u >> 16);
}
__device__ __forceinline__ float bf2f(u16 h) {
    return __uint_as_float(((unsigned)h) << 16);
}

__device__ __forceinline__ float waveReduceSum(float v) {
#pragma unroll
    for (int off = 32; off > 0; off >>= 1) v += __shfl_xor(v, off, 64);
    return v;
}

// ---------------------------------------------------------------------------
// fp32 -> bf16 elementwise convert (weights). n % 4 == 0.
// ---------------------------------------------------------------------------
__global__ __launch_bounds__(256) void convert_bf16_k(const float* __restrict__ in,
                                                      u16* __restrict__ out, int n) {
    int i = (blockIdx.x * 256 + threadIdx.x) * 4;
    if (i >= n) return;
    float4 v = *(const float4*)(in + i);
    ushort4 o = make_ushort4(f2bf(v.x), f2bf(v.y), f2bf(v.z), f2bf(v.w));
    *(ushort4*)(out + i) = o;
}

// ---------------------------------------------------------------------------
// x [B][C][N] fp32 -> xT [B][N][C] bf16.  64x64 tiles via LDS.
// grid = (N/64, C/64, B), block 256.
// ---------------------------------------------------------------------------
__global__ __launch_bounds__(256) void transpose_x(const float* __restrict__ x,
                                                   u16* __restrict__ xT) {
    __shared__ float tile[64][65];
    const int n0 = blockIdx.x * 64;
    const int c0 = blockIdx.y * 64;
    const size_t b = blockIdx.z;
    const float* xb = x + b * (size_t)(C_IN * N_LOC);
    u16* xtb = xT + b * (size_t)(N_LOC * C_IN);
    const int tid = threadIdx.x;

    const int jn = (tid & 15) * 4;
    const int cr = tid >> 4;
#pragma unroll
    for (int r = 0; r < 4; ++r) {
        int c = cr + r * 16;
        float4 v = *(const float4*)(xb + (size_t)(c0 + c) * N_LOC + n0 + jn);
        tile[c][jn + 0] = v.x;
        tile[c][jn + 1] = v.y;
        tile[c][jn + 2] = v.z;
        tile[c][jn + 3] = v.w;
    }
    __syncthreads();
    const int c4 = (tid & 15) * 4;
#pragma unroll
    for (int r = 0; r < 4; ++r) {
        int n = (tid >> 4) + r * 16;
        ushort4 o = make_ushort4(f2bf(tile[c4 + 0][n]), f2bf(tile[c4 + 1][n]),
                                 f2bf(tile[c4 + 2][n]), f2bf(tile[c4 + 3][n]));
        *(ushort4*)(xtb + (size_t)(n0 + n) * C_IN + c0 + c4) = o;
    }
}

// ---------------------------------------------------------------------------
// 8-phase 256x256 bf16 MFMA GEMM, dual weight/output select.
// 512 threads = 8 waves (2M x 4N). Wave output rows: {mh*128 + wr*64 ..+63},
// cols {nh*128 + wc*32 ..+31} per quadrant (mh,nh). acc[mh*4+mi][nh*2+ni].
// LDS per buf: A 256x64 + B 256x64 bf16; halves = 128 rows; XOR swizzle
// slot = chunk ^ (row&7) on both write-source and read.
// Per K-tile t (buf db=t&1), phases:
//  p0: read av(lo)+bw0(lo) | stage (t+1, A-hi)->db^1 | MFMA q(0,0)
//  p1: read bw1(hi)        | stage (t+2, A-lo)->db   | MFMA q(0,1)
//  p2: read av(hi)         | stage (t+2, B-hi)->db   | MFMA q(1,1)
//  p3: (reg reuse)         | stage (t+2, B-lo)->db   | MFMA q(1,0)
//  boundary: vmcnt(6) (or 0 at tail), barrier.
// Race-freedom: each region's last ds_read retires (lgkmcnt(0)) before the
// post-MFMA barrier preceding the phase that issues its overwrite.
// grid (4,4,B) with XCD-bijective remap (nwg=1024 % 8 == 0).
// ---------------------------------------------------------------------------
template <bool RELU>
__global__ __launch_bounds__(512, 2) void gemm256_dual(
        const u16* __restrict__ A, int lda,
        const u16* __restrict__ W0, const u16* __restrict__ W1,
        const float* __restrict__ b0, const float* __restrict__ b1,
        u16* __restrict__ O0, u16* __restrict__ O1, int ldo, int K) {
    __shared__ __align__(16) u16 As[2][256 * 64];
    __shared__ __align__(16) u16 Bs[2][256 * 64];
    const int tid = threadIdx.x;
    const int lane = tid & 63;
    const int wid = tid >> 6;
    const int wr = wid >> 2;   // 0..1
    const int wc = wid & 3;    // 0..3

    const int id = blockIdx.x + 4 * blockIdx.y + 16 * blockIdx.z;
    const int nid = (id & 7) * 128 + (id >> 3);
    const int bx = nid & 3;
    const int by = (nid >> 2) & 3;
    const int bz = nid >> 4;
    const int r0 = bx * 256;
    const int c0 = by * 256;

    const bool sel = (c0 >= 512);
    const u16* Wt = sel ? W1 : W0;
    const float* bt = sel ? b1 : b0;
    u16* Ot = sel ? O1 : O0;
    const int cb = sel ? (c0 - 512) : c0;

    const u16* Ab = A + (size_t)bz * N_LOC * lda + (size_t)r0 * lda;
    const u16* Wb = Wt + (size_t)cb * K;

    f32x4 acc[8][4];
#pragma unroll
    for (int mi = 0; mi < 8; ++mi)
#pragma unroll
        for (int ni = 0; ni < 4; ++ni)
            acc[mi][ni] = (f32x4){0.f, 0.f, 0.f, 0.f};

    const int nk = K / 64;            // >= 2 always here (12 or 8)
    const int srow = tid >> 3;        // 0..63
    const int schunk = tid & 7;

    // stage half (0 = rows 0..127, 1 = rows 128..255) of K-tile kt into buf db.
    // dest is linear (wave-uniform + lane*16); source chunk pre-swizzled.
#define STG(db_, kt_, isB, half)                                               \
    do {                                                                       \
        const u16* gsrc_ = (isB) ? Wb : Ab;                                    \
        const int gstr_ = (isB) ? K : lda;                                     \
        u16* ldst_ = (isB) ? &Bs[db_][0] : &As[db_][0];                        \
        const int kb_ = (kt_) * 64;                                            \
        {                                                                      \
            int row_ = (half) * 128 + srow;                                    \
            int s_ = schunk ^ (row_ & 7);                                      \
            load_lds16(gsrc_ + (size_t)row_ * gstr_ + kb_ + s_ * 8,            \
                       ldst_ + (half) * 8192 + tid * 8);                       \
        }                                                                      \
        {                                                                      \
            int row_ = (half) * 128 + 64 + srow;                               \
            int s_ = schunk ^ (row_ & 7);                                      \
            load_lds16(gsrc_ + (size_t)row_ * gstr_ + kb_ + s_ * 8,            \
                       ldst_ + (half) * 8192 + 4096 + tid * 8);                \
        }                                                                      \
    } while (0)

#define SLOT(kk) ((((kk) * 4 + (lane >> 4)) ^ (lane & 7)) * 8)

#define PHASE_MID()                                                            \
    __builtin_amdgcn_s_barrier();                                              \
    asm volatile("s_waitcnt lgkmcnt(0)" ::: "memory");                         \
    __builtin_amdgcn_sched_barrier(0);                                         \
    __builtin_amdgcn_s_setprio(1)

#define PHASE_END()                                                            \
    __builtin_amdgcn_s_setprio(0);                                             \
    __builtin_amdgcn_sched_barrier(0);                                         \
    __builtin_amdgcn_s_barrier()

    // ---- prologue: tile0 all 4 halves -> buf0; tile1 {A-lo, B-hi, B-lo} -> buf1
    STG(0, 0, 0, 0); STG(0, 0, 0, 1);
    STG(0, 0, 1, 0); STG(0, 0, 1, 1);
    STG(1, 1, 0, 0);
    STG(1, 1, 1, 1);
    STG(1, 1, 1, 0);
    asm volatile("s_waitcnt vmcnt(6)" ::: "memory");   // tile0 fully landed
    __builtin_amdgcn_s_barrier();

    for (int t = 0; t < nk; ++t) {
        const int db = t & 1;
        const u16* uA = &As[db][0];
        const u16* uB = &Bs[db][0];
        bf16x8 av[4][2], bw0[2][2], bw1[2][2];

        // ===== phase 0 : quadrant (mh=0, nh=0)
#pragma unroll
        for (int mi = 0; mi < 4; ++mi)
#pragma unroll
            for (int kk = 0; kk < 2; ++kk)
                av[mi][kk] = *(const bf16x8*)
                    &uA[(wr * 64 + mi * 16 + (lane & 15)) * 64 + SLOT(kk)];
#pragma unroll
        for (int ni = 0; ni < 2; ++ni)
#pragma unroll
            for (int kk = 0; kk < 2; ++kk)
                bw0[ni][kk] = *(const bf16x8*)
                    &uB[(wc * 32 + ni * 16 + (lane & 15)) * 64 + SLOT(kk)];
        if (t + 1 < nk) STG(db ^ 1, t + 1, 0, 1);
        PHASE_MID();
#pragma unroll
        for (int mi = 0; mi < 4; ++mi)
#pragma unroll
            for (int ni = 0; ni < 2; ++ni)
#pragma unroll
                for (int kk = 0; kk < 2; ++kk)
                    acc[mi][ni] = __builtin_amdgcn_mfma_f32_16x16x32_bf16(
                        av[mi][kk], bw0[ni][kk], acc[mi][ni], 0, 0, 0);
        PHASE_END();

        // ===== phase 1 : quadrant (mh=0, nh=1)
#pragma unroll
        for (int ni = 0; ni < 2; ++ni)
#pragma unroll
            for (int kk = 0; kk < 2; ++kk)
                bw1[ni][kk] = *(const bf16x8*)
                    &uB[(128 + wc * 32 + ni * 16 + (lane & 15)) * 64 + SLOT(kk)];
        if (t + 2 < nk) STG(db, t + 2, 0, 0);
        PHASE_MID();
#pragma unroll
        for (int mi = 0; mi < 4; ++mi)
#pragma unroll
            for (int ni = 0; ni < 2; ++ni)
#pragma unroll
                for (int kk = 0; kk < 2; ++kk)
                    acc[mi][2 + ni] = __builtin_amdgcn_mfma_f32_16x16x32_bf16(
                        av[mi][kk], bw1[ni][kk], acc[mi][2 + ni], 0, 0, 0);
        PHASE_END();

        // ===== phase 2 : quadrant (mh=1, nh=1)
#pragma unroll
        for (int mi = 0; mi < 4; ++mi)
#pragma unroll
            for (int kk = 0; kk < 2; ++kk)
                av[mi][kk] = *(const bf16x8*)
                    &uA[(128 + wr * 64 + mi * 16 + (lane & 15)) * 64 + SLOT(kk)];
        if (t + 2 < nk) STG(db, t + 2, 1, 1);
        PHASE_MID();
#pragma unroll
        for (int mi = 0; mi < 4; ++mi)
#pragma unroll
            for (int ni = 0; ni < 2; ++ni)
#pragma unroll
                for (int kk = 0; kk < 2; ++kk)
                    acc[4 + mi][2 + ni] = __builtin_amdgcn_mfma_f32_16x16x32_bf16(
                        av[mi][kk], bw1[ni][kk], acc[4 + mi][2 + ni], 0, 0, 0);
        PHASE_END();

        // ===== phase 3 : quadrant (mh=1, nh=0), pure register reuse
        if (t + 2 < nk) STG(db, t + 2, 1, 0);
        PHASE_MID();
#pragma unroll
        for (int mi = 0; mi < 4; ++mi)
#pragma unroll
            for (int ni = 0; ni < 2; ++ni)
#pragma unroll
                for (int kk = 0; kk < 2; ++kk)
                    acc[4 + mi][ni] = __builtin_amdgcn_mfma_f32_16x16x32_bf16(
                        av[mi][kk], bw0[ni][kk], acc[4 + mi][ni], 0, 0, 0);
        __builtin_amdgcn_s_setprio(0);
        __builtin_amdgcn_sched_barrier(0);
        if (t + 2 < nk)
            asm volatile("s_waitcnt vmcnt(6)" ::: "memory");
        else
            asm volatile("s_waitcnt vmcnt(0)" ::: "memory");
        __builtin_amdgcn_s_barrier();   // next tile fully visible to all waves
    }
#undef STG
#undef SLOT
#undef PHASE_MID
#undef PHASE_END

    float bv[2][2];
#pragma unroll
    for (int nh = 0; nh < 2; ++nh)
#pragma unroll
        for (int ni = 0; ni < 2; ++ni)
            bv[nh][ni] = bt[cb + nh * 128 + wc * 32 + ni * 16 + (lane & 15)];
    u16* Ob = Ot + (size_t)bz * N_LOC * ldo;
#pragma unroll
    for (int mh = 0; mh < 2; ++mh)
#pragma unroll
        for (int mi = 0; mi < 4; ++mi)
#pragma unroll
            for (int rr = 0; rr < 4; ++rr) {
                int row = r0 + mh * 128 + wr * 64 + mi * 16 + (lane >> 4) * 4 + rr;
#pragma unroll
                for (int nh = 0; nh < 2; ++nh)
#pragma unroll
                    for (int ni = 0; ni < 2; ++ni) {
                        int col = cb + nh * 128 + wc * 32 + ni * 16 + (lane & 15);
                        float v = acc[mh * 4 + mi][nh * 2 + ni][rr] + bv[nh][ni];
                        if (RELU) v = fmaxf(v, 0.f);
                        Ob[(size_t)row * ldo + col] = f2bf(v);
                    }
            }
}

// ---------------------------------------------------------------------------
// m97-style 128xBN MFMA GEMM (stage-2, unchanged).
// grid = (N_LOC/128, S/BN, B), 256 threads (2x2 waves).
// ---------------------------------------------------------------------------
template <int BN, bool RELU>
__global__ __launch_bounds__(256) void gemm_bf16(const u16* __restrict__ A, int lda,
                                                 const u16* __restrict__ W,
                                                 const float* __restrict__ bias,
                                                 u16* __restrict__ Out, int ldo, int K) {
    constexpr int WN = BN / 2;
    constexpr int FN = WN / 16;
    __shared__ __align__(16) u16 As[128 * 64];
    __shared__ __align__(16) u16 Bs[BN * 64];
    const int tid = threadIdx.x;
    const int lane = tid & 63;
    const int wv = tid >> 6;
    const int wr = wv >> 1;
    const int wc = wv & 1;
    const int r0 = blockIdx.x * 128;
    const int c0 = blockIdx.y * BN;
    const size_t bb = blockIdx.z;
    const u16* Ab = A + bb * (size_t)N_LOC * lda + (size_t)r0 * lda;
    const u16* Wb = W + (size_t)c0 * K;

    f32x4 acc[4][FN];
#pragma unroll
    for (int mi = 0; mi < 4; ++mi)
#pragma unroll
        for (int ni = 0; ni < FN; ++ni)
            acc[mi][ni] = (f32x4){0.f, 0.f, 0.f, 0.f};

    const int srow = tid >> 3;
    const int scol = (tid & 7) * 8;

    const int nk = K / 64;
    for (int kt = 0; kt < nk; ++kt) {
        const int kbase = kt * 64 + scol;
#pragma unroll
        for (int j = 0; j < 4; ++j) {
            int row = j * 32 + srow;
            load_lds16(Ab + (size_t)row * lda + kbase, &As[(size_t)(j * 256 + tid) * 8]);
        }
#pragma unroll
        for (int j = 0; j < BN / 32; ++j) {
            int row = j * 32 + srow;
            load_lds16(Wb + (size_t)row * K + kbase, &Bs[(size_t)(j * 256 + tid) * 8]);
        }
        __syncthreads();
#pragma unroll
        for (int kk = 0; kk < 2; ++kk) {
            bf16x8 av[4], bw[FN];
#pragma unroll
            for (int mi = 0; mi < 4; ++mi)
                av[mi] = *(const bf16x8*)&As[(wr * 64 + mi * 16 + (lane & 15)) * 64 +
                                             kk * 32 + (lane >> 4) * 8];
#pragma unroll
            for (int ni = 0; ni < FN; ++ni)
                bw[ni] = *(const bf16x8*)&Bs[(wc * WN + ni * 16 + (lane & 15)) * 64 +
                                             kk * 32 + (lane >> 4) * 8];
#pragma unroll
            for (int mi = 0; mi < 4; ++mi)
#pragma unroll
                for (int ni = 0; ni < FN; ++ni)
                    acc[mi][ni] = __builtin_amdgcn_mfma_f32_16x16x32_bf16(
                        av[mi], bw[ni], acc[mi][ni], 0, 0, 0);
        }
        __syncthreads();
    }

    float bv[FN];
#pragma unroll
    for (int ni = 0; ni < FN; ++ni)
        bv[ni] = bias[c0 + wc * WN + ni * 16 + (lane & 15)];
    u16* Ob = Out + bb * (size_t)N_LOC * ldo;
#pragma unroll
    for (int mi = 0; mi < 4; ++mi) {
#pragma unroll
        for (int r = 0; r < 4; ++r) {
            int row = r0 + wr * 64 + mi * 16 + (lane >> 4) * 4 + r;
#pragma unroll
            for (int ni = 0; ni < FN; ++ni) {
                int col = c0 + wc * WN + ni * 16 + (lane & 15);
                float v = acc[mi][ni][r] + bv[ni];
                if (RELU) v = fmaxf(v, 0.f);
                Ob[(size_t)row * ldo + col] = f2bf(v);
            }
        }
    }
}

// ---------------------------------------------------------------------------
// Token MLP stage 1: hidb[b][j] = relu(t[b] . tw1[j] + tb1[j]); grid (8,B).
// ---------------------------------------------------------------------------
__global__ __launch_bounds__(256) void tok1_kernel(const float* __restrict__ t,
                                                   const float* __restrict__ tw1,
                                                   const float* __restrict__ tb1,
                                                   float* __restrict__ hidb) {
    __shared__ __align__(16) float tl[C_IN];
    const int b = blockIdx.y;
    const int j0 = blockIdx.x * 64;
    const int tid = threadIdx.x;
    const int lane = tid & 63;
    const int wave = tid >> 6;
    for (int i = tid; i < C_IN; i += 256) tl[i] = t[(size_t)b * C_IN + i];
    __syncthreads();
    for (int j = wave; j < 64; j += 4) {
        const int row = j0 + j;
        const float4* wr = (const float4*)(tw1 + (size_t)row * C_IN);
        const float4* tr = (const float4*)tl;
        float s = 0.f;
#pragma unroll
        for (int q = 0; q < 3; ++q) {
            float4 wv = wr[lane + 64 * q];
            float4 tv = tr[lane + 64 * q];
            s += wv.x * tv.x + wv.y * tv.y + wv.z * tv.z + wv.w * tv.w;
        }
        s = waveReduceSum(s);
        if (lane == 0) hidb[(size_t)b * HID + row] = fmaxf(s + tb1[row], 0.f);
    }
}

// ---------------------------------------------------------------------------
// Token MLP stage 2: tok[b][g] = hidb[b] . tw2[g] + tb2[g]; grid (4,B).
// ---------------------------------------------------------------------------
__global__ __launch_bounds__(256) void tok2_kernel(const float* __restrict__ hidb,
                                                   const float* __restrict__ tw2,
                                                   const float* __restrict__ tb2,
                                                   float* __restrict__ tok) {
    __shared__ __align__(16) float hl[HID];
    const int b = blockIdx.y;
    const int g0 = blockIdx.x * 64;
    const int tid = threadIdx.x;
    const int lane = tid & 63;
    const int wave = tid >> 6;
    for (int i = tid; i < HID; i += 256) hl[i] = hidb[(size_t)b * HID + i];
    __syncthreads();
    for (int j = wave; j < 64; j += 4) {
        const int row = g0 + j;
        const float4* wr = (const float4*)(tw2 + (size_t)row * HID);
        const float4* hr = (const float4*)hl;
        float s = 0.f;
#pragma unroll
        for (int q = 0; q < 2; ++q) {
            float4 wv = wr[lane + 64 * q];
            float4 hv = hr[lane + 64 * q];
            s += wv.x * hv.x + wv.y * hv.y + wv.z * hv.z + wv.w * hv.w;
        }
        s = waveReduceSum(s);
        if (lane == 0) tok[(size_t)b * G_DIM + row] = s + tb2[row];
    }
}

// ---------------------------------------------------------------------------
// Sinkhorn: pT [B][N][M] bf16 -> PT [B][N][M] fp32. One block/batch.
// ---------------------------------------------------------------------------
__global__ __launch_bounds__(1024) void sinkhorn_kernel(const u16* __restrict__ pT,
                                                        const float* __restrict__ dust,
                                                        float* __restrict__ PT) {
    __shared__ u16 sp[M_DIM][N_LOC];
    __shared__ float u[M_DIM + 1];
    __shared__ float v[N_LOC];
    const int b = blockIdx.x;
    const int t = threadIdx.x;
    const int lane = t & 63;
    const int wave = t >> 6;
    const float alpha = dust[0];
    const float norm = -__logf(1088.f);
    const float logmu_main = norm;
    const float logmu_last = __logf(960.f) + norm;
    const float lognu = norm;

    const uint4* prow = (const uint4*)(pT + ((size_t)b * N_LOC + t) * M_DIM);
#pragma unroll
    for (int q = 0; q < 8; ++q) {
        uint4 ch = prow[q];
        sp[q * 8 + 0][t] = (u16)(ch.x);
        sp[q * 8 + 1][t] = (u16)(ch.x >> 16);
        sp[q * 8 + 2][t] = (u16)(ch.y);
        sp[q * 8 + 3][t] = (u16)(ch.y >> 16);
        sp[q * 8 + 4][t] = (u16)(ch.z);
        sp[q * 8 + 5][t] = (u16)(ch.z >> 16);
        sp[q * 8 + 6][t] = (u16)(ch.w);
        sp[q * 8 + 7][t] = (u16)(ch.w >> 16);
    }
    v[t] = 0.f;
    if (t < M_DIM + 1) u[t] = 0.f;
    __syncthreads();

    for (int it = 0; it < 3; ++it) {
        for (int m = wave; m < M_DIM + 1; m += 16) {
            float s = 0.f;
            if (m < M_DIM) {
#pragma unroll
                for (int q = 0; q < 16; ++q) {
                    int c = lane + 64 * q;
                    s += __expf(bf2f(sp[m][c]) + v[c]);
                }
            } else {
#pragma unroll
                for (int q = 0; q < 16; ++q) {
                    int c = lane + 64 * q;
                    s += __expf(alpha + v[c]);
                }
            }
            s = waveReduceSum(s);
            if (lane == 0) u[m] = ((m < M_DIM) ? logmu_main : logmu_last) - __logf(s);
        }
        __syncthreads();
        float s = 0.f;
#pragma unroll 8
        for (int m = 0; m < M_DIM; ++m) s += __expf(bf2f(sp[m][t]) + u[m]);
        s += __expf(alpha + u[M_DIM]);
        v[t] = lognu - __logf(s);
        __syncthreads();
    }

    const float vt = v[t];
    float* Prow = PT + ((size_t)b * N_LOC + t) * M_DIM;
#pragma unroll
    for (int m4 = 0; m4 < M_DIM; m4 += 4) {
        float4 o;
        o.x = __expf(bf2f(sp[m4 + 0][t]) + u[m4 + 0] + vt - norm);
        o.y = __expf(bf2f(sp[m4 + 1][t]) + u[m4 + 1] + vt - norm);
        o.z = __expf(bf2f(sp[m4 + 2][t]) + u[m4 + 2] + vt - norm);
        o.w = __expf(bf2f(sp[m4 + 3][t]) + u[m4 + 3] + vt - norm);
        *(float4*)(Prow + m4) = o;
    }
}

// ---------------------------------------------------------------------------
// agg[b,l,m] = sum_n fT[b,n,l] * PT[b,n,m]. grid (4,B), 256 thr.
// ---------------------------------------------------------------------------
__global__ __launch_bounds__(256) void agg_kernel(const u16* __restrict__ fT,
                                                  const float* __restrict__ PT,
                                                  float* __restrict__ agg) {
    __shared__ float Fs[64][36];
    __shared__ float Ps[64][68];
    const int b = blockIdx.y;
    const int l0 = blockIdx.x * 32;
    const int tid = threadIdx.x;
    const u16* fb = fT + (size_t)b * N_LOC * L_DIM;
    const float* Pb = PT + (size_t)b * N_LOC * M_DIM;

    const int sn = tid >> 2;
    const int flc = (tid & 3) * 8;
    const int pmc = (tid & 3) * 16;
    const int tl = (tid >> 4) * 2;
    const int tm = (tid & 15) * 4;

    float acc[2][4] = {};

    for (int n0 = 0; n0 < N_LOC; n0 += 64) {
        __syncthreads();
        {
            uint4 ld = *(const uint4*)(fb + (size_t)(n0 + sn) * L_DIM + l0 + flc);
            Fs[sn][flc + 0] = bf2f((u16)(ld.x));
            Fs[sn][flc + 1] = bf2f((u16)(ld.x >> 16));
            Fs[sn][flc + 2] = bf2f((u16)(ld.y));
            Fs[sn][flc + 3] = bf2f((u16)(ld.y >> 16));
            Fs[sn][flc + 4] = bf2f((u16)(ld.z));
            Fs[sn][flc + 5] = bf2f((u16)(ld.z >> 16));
            Fs[sn][flc + 6] = bf2f((u16)(ld.w));
            Fs[sn][flc + 7] = bf2f((u16)(ld.w >> 16));
        }
#pragma unroll
        for (int i = 0; i < 4; ++i) {
            float4 vv = *(const float4*)(Pb + (size_t)(n0 + sn) * M_DIM + pmc + 4 * i);
            *(float4*)&Ps[sn][pmc + 4 * i] = vv;
        }
        __syncthreads();
#pragma unroll 8
        for (int nn = 0; nn < 64; ++nn) {
            float a0 = Fs[nn][tl];
            float a1 = Fs[nn][tl + 1];
            float4 p4 = *(const float4*)&Ps[nn][tm];
            acc[0][0] = fmaf(a0, p4.x, acc[0][0]);
            acc[0][1] = fmaf(a0, p4.y, acc[0][1]);
            acc[0][2] = fmaf(a0, p4.z, acc[0][2]);
            acc[0][3] = fmaf(a0, p4.w, acc[0][3]);
            acc[1][0] = fmaf(a1, p4.x, acc[1][0]);
            acc[1][1] = fmaf(a1, p4.y, acc[1][1]);
            acc[1][2] = fmaf(a1, p4.z, acc[1][2]);
            acc[1][3] = fmaf(a1, p4.w, acc[1][3]);
        }
    }

#pragma unroll
    for (int i = 0; i < 2; ++i) {
        float* dst = agg + ((size_t)b * L_DIM + l0 + tl + i) * M_DIM + tm;
        *(float4*)dst = make_float4(acc[i][0], acc[i][1], acc[i][2], acc[i][3]);
    }
}

// ---------------------------------------------------------------------------
// Final normalization cascade.
// ---------------------------------------------------------------------------
__global__ __launch_bounds__(256) void final_kernel(const float* __restrict__ agg,
                                                    const float* __restrict__ tok,
                                                    float* __restrict__ out) {
    __shared__ __align__(16) float ag[L_DIM * M_DIM];
    __shared__ float rm[M_DIM];
    __shared__ float red[4];
    __shared__ float tk[G_DIM];
    const int b = blockIdx.x;
    const int tid = threadIdx.x;
    const int lane = tid & 63;
    const int wave = tid >> 6;
    const float EPS = 1e-12f;

    const float4* ab = (const float4*)(agg + (size_t)b * L_DIM * M_DIM);
    for (int e4 = tid; e4 < L_DIM * M_DIM / 4; e4 += 256) ((float4*)ag)[e4] = ab[e4];
    tk[tid] = tok[(size_t)b * G_DIM + tid];
    __syncthreads();

    if (tid < M_DIM) {
        float ss = 0.f;
#pragma unroll 8
        for (int l = 0; l < L_DIM; ++l) {
            float x = ag[l * M_DIM + tid];
            ss = fmaf(x, x, ss);
        }
        rm[tid] = 1.f / fmaxf(sqrtf(ss), EPS);
    }
    const float tv = tk[tid];
    float ssl = tv * tv;
    ssl = waveReduceSum(ssl);
    if (lane == 0) red[wave] = ssl;
    __syncthreads();
    const float stok = red[0] + red[1] + red[2] + red[3];
    const float rt = 1.f / fmaxf(sqrtf(stok), EPS);
    const float tn = tv * rt;

    float gs = tn * tn;
    for (int e = tid; e < L_DIM * M_DIM; e += 256) {
        float x = ag[e] * rm[e & (M_DIM - 1)];
        gs = fmaf(x, x, gs);
    }
    __syncthreads();
    gs = waveReduceSum(gs);
    if (lane == 0) red[wave] = gs;
    __syncthreads();
    const float G = red[0] + red[1] + red[2] + red[3];
    const float rg = 1.f / fmaxf(sqrtf(G), EPS);

    float* ob = out + (size_t)b * (G_DIM + L_DIM * M_DIM);
    ob[tid] = tn * rg;
    for (int e = tid; e < L_DIM * M_DIM; e += 256)
        ob[G_DIM + e] = ag[e] * rm[e & (M_DIM - 1)] * rg;
}

// ---------------------------------------------------------------------------
extern "C" void kernel_launch(void* const* d_in, const int* in_sizes, int n_in,
                              void* d_out, int out_size, void* d_ws, size_t ws_size,
                              hipStream_t stream) {
    const float* x    = (const float*)d_in[0];
    const float* t    = (const float*)d_in[1];
    const float* tw1  = (const float*)d_in[2];
    const float* tb1  = (const float*)d_in[3];
    const float* tw2  = (const float*)d_in[4];
    const float* tb2  = (const float*)d_in[5];
    const float* cw1  = (const float*)d_in[6];
    const float* cb1  = (const float*)d_in[7];
    const float* cw2  = (const float*)d_in[8];
    const float* cb2  = (const float*)d_in[9];
    const float* sw1  = (const float*)d_in[10];
    const float* sb1  = (const float*)d_in[11];
    const float* sw2  = (const float*)d_in[12];
    const float* sb2  = (const float*)d_in[13];
    const float* dust = (const float*)d_in[14];
    float* out = (float*)d_out;

    char* ws = (char*)d_ws;
    u16* xT    = (u16*)(ws);                         // 100,663,296
    u16* hbuf  = (u16*)(ws + 100663296ull);          //  67,108,864
    u16* sbuf  = (u16*)(ws + 167772160ull);          //  67,108,864
    u16* fT    = (u16*)(ws + 234881024ull);          //  16,777,216
    u16* pT    = (u16*)(ws + 251658240ull);          //   8,388,608
    u16* cw1b  = (u16*)(ws + 260046848ull);          //     786,432
    u16* sw1b  = (u16*)(ws + 260833280ull);          //     786,432
    u16* cw2b  = (u16*)(ws + 261619712ull);          //     131,072
    u16* sw2b  = (u16*)(ws + 261750784ull);          //      65,536
    float* hidb = (float*)(ws + 261816320ull);       //     131,072
    // reuse of dead xT region after stage-1:
    float* PT     = (float*)(ws);                    //  16,777,216
    float* tokbuf = (float*)(ws + 20971520ull);      //      65,536
    float* aggbuf = (float*)(ws + 25165824ull);      //   2,097,152

    convert_bf16_k<<<(HID * C_IN / 4 + 255) / 256, 256, 0, stream>>>(cw1, cw1b, HID * C_IN);
    convert_bf16_k<<<(HID * C_IN / 4 + 255) / 256, 256, 0, stream>>>(sw1, sw1b, HID * C_IN);
    convert_bf16_k<<<(L_DIM * HID / 4 + 255) / 256, 256, 0, stream>>>(cw2, cw2b, L_DIM * HID);
    convert_bf16_k<<<(M_DIM * HID / 4 + 255) / 256, 256, 0, stream>>>(sw2, sw2b, M_DIM * HID);
    transpose_x<<<dim3(N_LOC / 64, C_IN / 64, B_SZ), 256, 0, stream>>>(x, xT);

    // merged stage-1, 8-phase 256x256: col-tiles 0-1 -> hbuf (cw1),
    // col-tiles 2-3 -> sbuf (sw1).
    gemm256_dual<true><<<dim3(4, 4, B_SZ), 512, 0, stream>>>(
        xT, C_IN, cw1b, sw1b, cb1, sb1, hbuf, sbuf, HID, C_IN);

    // stage-2 (compact lda=512)
    gemm_bf16<128, false><<<dim3(8, 1, B_SZ), 256, 0, stream>>>(
        hbuf, HID, cw2b, cb2, fT, L_DIM, HID);
    gemm_bf16<64, false><<<dim3(8, 1, B_SZ), 256, 0, stream>>>(
        sbuf, HID, sw2b, sb2, pT, M_DIM, HID);

    tok1_kernel<<<dim3(HID / 64, B_SZ), 256, 0, stream>>>(t, tw1, tb1, hidb);
    tok2_kernel<<<dim3(G_DIM / 64, B_SZ), 256, 0, stream>>>(hidb, tw2, tb2, tokbuf);

    sinkhorn_kernel<<<B_SZ, 1024, 0, stream>>>(pT, dust, PT);
    agg_kernel<<<dim3(L_DIM / 32, B_SZ), 256, 0, stream>>>(fT, PT, aggbuf);
    final_kernel<<<B_SZ, 256, 0, stream>>>(aggbuf, tokbuf, out);
}

// Round 7
// 350.498 us; speedup vs baseline: 1.0718x; 1.0045x over previous
//
#include <hip/hip_runtime.h>
#include <math.h>

// ---------------------------------------------------------------------------
// SALAD forward, round 7: fused stage-1+stage-2 GEMM. Per block: 128 rows x
// full 512 hid (K=768, BK=32, 2-phase counted-vmcnt schedule), h handed off
// through LDS (k-chunk-major, conflict-free), then in-block stage-2
// (f = h.cw2^T or p = h.sw2^T) with W2 read from global (L2-resident).
// Eliminates the 131 MB h round-trip and 2 dispatches. Converts merged.
// B=64, C=768, N=1024, HID=512, L=128, M=64, G=256.
// ---------------------------------------------------------------------------

#define B_SZ   64
#define C_IN   768
#define N_LOC  1024
#define HID    512
#define L_DIM  128
#define M_DIM  64
#define G_DIM  256

typedef unsigned short u16;
typedef __bf16 bf16x8 __attribute__((ext_vector_type(8)));
typedef float f32x4 __attribute__((ext_vector_type(4)));

typedef const __attribute__((address_space(1))) void* gptr_t;
typedef __attribute__((address_space(3))) void* sptr_t;

__device__ __forceinline__ void load_lds16(const void* g, void* l) {
    __builtin_amdgcn_global_load_lds((gptr_t)g, (sptr_t)l, 16, 0, 0);
}

__device__ __forceinline__ u16 f2bf(float f) {  // round-to-nearest-even
    unsigned u = __float_as_uint(f);
    u += 0x7fffu + ((u >> 16) & 1u);
    return (u16)(u >> 16);
}
__device__ __forceinline__ float bf2f(u16 h) {
    return __uint_as_float(((unsigned)h) << 16);
}

__device__ __forceinline__ float waveReduceSum(float v) {
#pragma unroll
    for (int off = 32; off > 0; off >>= 1) v += __shfl_xor(v, off, 64);
    return v;
}

// ---------------------------------------------------------------------------
// All four weight converts in one dispatch. Segment sizes in float4 units:
// cw1/sw1: 98304 each, cw2: 16384, sw2: 8192. Total 221184 -> 864 blocks.
// ---------------------------------------------------------------------------
__global__ __launch_bounds__(256) void convert_all(
        const float* __restrict__ cw1, const float* __restrict__ sw1,
        const float* __restrict__ cw2, const float* __restrict__ sw2,
        u16* __restrict__ cw1b, u16* __restrict__ sw1b,
        u16* __restrict__ cw2b, u16* __restrict__ sw2b) {
    int i4 = blockIdx.x * 256 + threadIdx.x;
    const float* src; u16* dst; int base;
    if (i4 < 98304)       { src = cw1; dst = cw1b; base = 0; }
    else if (i4 < 196608) { src = sw1; dst = sw1b; base = 98304; }
    else if (i4 < 212992) { src = cw2; dst = cw2b; base = 196608; }
    else if (i4 < 221184) { src = sw2; dst = sw2b; base = 212992; }
    else return;
    int j = (i4 - base) * 4;
    float4 v = *(const float4*)(src + j);
    *(ushort4*)(dst + j) = make_ushort4(f2bf(v.x), f2bf(v.y), f2bf(v.z), f2bf(v.w));
}

// ---------------------------------------------------------------------------
// x [B][C][N] fp32 -> xT [B][N][C] bf16.  64x64 tiles via LDS.
// grid = (N/64, C/64, B), block 256.
// ---------------------------------------------------------------------------
__global__ __launch_bounds__(256) void transpose_x(const float* __restrict__ x,
                                                   u16* __restrict__ xT) {
    __shared__ float tile[64][65];
    const int n0 = blockIdx.x * 64;
    const int c0 = blockIdx.y * 64;
    const size_t b = blockIdx.z;
    const float* xb = x + b * (size_t)(C_IN * N_LOC);
    u16* xtb = xT + b * (size_t)(N_LOC * C_IN);
    const int tid = threadIdx.x;

    const int jn = (tid & 15) * 4;
    const int cr = tid >> 4;
#pragma unroll
    for (int r = 0; r < 4; ++r) {
        int c = cr + r * 16;
        float4 v = *(const float4*)(xb + (size_t)(c0 + c) * N_LOC + n0 + jn);
        tile[c][jn + 0] = v.x;
        tile[c][jn + 1] = v.y;
        tile[c][jn + 2] = v.z;
        tile[c][jn + 3] = v.w;
    }
    __syncthreads();
    const int c4 = (tid & 15) * 4;
#pragma unroll
    for (int r = 0; r < 4; ++r) {
        int n = (tid >> 4) + r * 16;
        ushort4 o = make_ushort4(f2bf(tile[c4 + 0][n]), f2bf(tile[c4 + 1][n]),
                                 f2bf(tile[c4 + 2][n]), f2bf(tile[c4 + 3][n]));
        *(ushort4*)(xtb + (size_t)(n0 + n) * C_IN + c0 + c4) = o;
    }
}

// ---------------------------------------------------------------------------
// Fused stage-1 + stage-2.
// Stage-1: h[128 n][512 c] = relu(xT[128xK=768] . W1^T + b1), BK=32, nk=24.
//   8 waves (2 row-halves x 4 col-quarters); per wave 64x128; acc1[4][8].
//   LDS (union, 128 KiB):
//     stage-1: A[2 buf][4 kchunk][128 n][8] bf16 (8 KiB/buf) at 0;
//              B[2 buf][4 kchunk][512 c][8] bf16 (32 KiB/buf) at 8192 u16.
//     k-chunk-major => 16-lane row-walk reads hit all banks (no swizzle).
//   Schedule/tile t (buf db=t&1), 2 phases:
//     ph0: ds_read av[0..3]+bw[0..3] | stage B(t+1)->db^1 (4 calls)
//          | barrier, lgkm(0), 16 MFMA (ni 0..3), barrier
//     ph1: ds_read bw[4..7]          | stage A(t+2)->db   (1 call)
//          | barrier, lgkm(0), 16 MFMA (ni 4..7)
//     boundary: vmcnt(1) (A(t+2) stays in flight; B(t+1) drained), barrier.
//   Race-freedom: A[db] last read ph0(t) -> overwrite issued ph1(t) after
//   ph0's lgkm+barrier; B[db^1] last read ph1(t-1) -> overwrite ph0(t).
// Handoff: h -> LDS [64 cchunk][128 n][8] bf16 (128 KiB), __syncthreads.
// Stage-2: Out2[128 n][S2] = h . W2^T + b2 (K=512, S2=128 f / 64 p);
//   av2 from h-LDS, W2 fragments straight from global (L2-resident),
//   no barriers. Scalar bf16 global stores (disjoint row-blocks).
// grid (8, 2, 64) XCD-bijective remap; 512 threads.
// ---------------------------------------------------------------------------
__global__ __launch_bounds__(512, 2) void fused12(
        const u16* __restrict__ xT,
        const u16* __restrict__ cw1b, const float* __restrict__ cb1,
        const u16* __restrict__ cw2b, const float* __restrict__ cb2,
        const u16* __restrict__ sw1b, const float* __restrict__ sb1,
        const u16* __restrict__ sw2b, const float* __restrict__ sb2,
        u16* __restrict__ fT, u16* __restrict__ pT) {
    __shared__ __align__(16) u16 LDSu[65536];   // 128 KiB union
    const int tid = threadIdx.x;
    const int lane = tid & 63;
    const int wid = tid >> 6;
    const int wr = wid >> 2;   // 0..1 : row half (64 rows)
    const int wc = wid & 3;    // 0..3 : col quarter (128 cols)

    const int id = blockIdx.x + 8 * blockIdx.y + 16 * blockIdx.z;
    const int nid = (id & 7) * 128 + (id >> 3);   // 1024 % 8 == 0, bijective
    const int bx = nid & 7;
    const int path = (nid >> 3) & 1;
    const int bz = nid >> 4;
    const int r0 = bx * 128;

    const u16* W1 = path ? sw1b : cw1b;
    const float* B1 = path ? sb1 : cb1;
    const u16* W2 = path ? sw2b : cw2b;
    const float* B2 = path ? sb2 : cb2;
    u16* O2 = path ? pT : fT;
    const int S2 = path ? M_DIM : L_DIM;

    const u16* Ab = xT + ((size_t)bz * N_LOC + r0) * C_IN;

    f32x4 acc1[4][8];
#pragma unroll
    for (int mi = 0; mi < 4; ++mi)
#pragma unroll
        for (int ni = 0; ni < 8; ++ni)
            acc1[mi][ni] = (f32x4){0.f, 0.f, 0.f, 0.f};

    const int nk = C_IN / 32;   // 24

    // dest linear = tid*16B; layout [kchunk][row][16B] falls out of tid split.
#define STG_A(db_, kt_)                                                        \
    load_lds16(Ab + (size_t)(tid & 127) * C_IN + (kt_) * 32 + (tid >> 7) * 8,  \
               &LDSu[(db_) * 4096 + tid * 8])
#define STG_B(db_, kt_)                                                        \
    do {                                                                       \
        _Pragma("unroll")                                                      \
        for (int j_ = 0; j_ < 4; ++j_)                                         \
            load_lds16(W1 + (size_t)tid * C_IN + (kt_) * 32 + j_ * 8,          \
                       &LDSu[8192 + (db_) * 16384 + j_ * 4096 + tid * 8]);     \
    } while (0)

#define AV_PTR(db_, mi_)                                                       \
    ((const bf16x8*)&LDSu[(db_) * 4096 + (lane >> 4) * 1024 +                  \
                          (64 * wr + 16 * (mi_) + (lane & 15)) * 8])
#define BW_PTR(db_, ni_)                                                       \
    ((const bf16x8*)&LDSu[8192 + (db_) * 16384 + (lane >> 4) * 4096 +          \
                          (128 * wc + 16 * (ni_) + (lane & 15)) * 8])

#define PHASE_MID()                                                            \
    __builtin_amdgcn_s_barrier();                                              \
    asm volatile("s_waitcnt lgkmcnt(0)" ::: "memory");                         \
    __builtin_amdgcn_sched_barrier(0);                                         \
    __builtin_amdgcn_s_setprio(1)

#define PHASE_END()                                                            \
    __builtin_amdgcn_s_setprio(0);                                             \
    __builtin_amdgcn_sched_barrier(0);                                         \
    __builtin_amdgcn_s_barrier()

    // prologue: tile0 (A+B), tile1 A. vmcnt(1): tile0 landed, A(1) in flight.
    STG_A(0, 0);
    STG_B(0, 0);
    STG_A(1, 1);
    asm volatile("s_waitcnt vmcnt(1)" ::: "memory");
    __builtin_amdgcn_s_barrier();

    for (int t = 0; t < nk; ++t) {
        const int db = t & 1;
        bf16x8 av[4], bwl[4], bwh[4];

        // ---- phase 0 : cols ni 0..3
#pragma unroll
        for (int mi = 0; mi < 4; ++mi) av[mi] = *AV_PTR(db, mi);
#pragma unroll
        for (int ni = 0; ni < 4; ++ni) bwl[ni] = *BW_PTR(db, ni);
        if (t + 1 < nk) STG_B(db ^ 1, t + 1);
        PHASE_MID();
#pragma unroll
        for (int mi = 0; mi < 4; ++mi)
#pragma unroll
            for (int ni = 0; ni < 4; ++ni)
                acc1[mi][ni] = __builtin_amdgcn_mfma_f32_16x16x32_bf16(
                    av[mi], bwl[ni], acc1[mi][ni], 0, 0, 0);
        PHASE_END();

        // ---- phase 1 : cols ni 4..7 (av reused from registers)
#pragma unroll
        for (int ni = 0; ni < 4; ++ni) bwh[ni] = *BW_PTR(db, 4 + ni);
        if (t + 2 < nk) STG_A(db, t + 2);
        PHASE_MID();
#pragma unroll
        for (int mi = 0; mi < 4; ++mi)
#pragma unroll
            for (int ni = 0; ni < 4; ++ni)
                acc1[mi][4 + ni] = __builtin_amdgcn_mfma_f32_16x16x32_bf16(
                    av[mi], bwh[ni], acc1[mi][4 + ni], 0, 0, 0);
        __builtin_amdgcn_s_setprio(0);
        __builtin_amdgcn_sched_barrier(0);
        if (t + 2 < nk)
            asm volatile("s_waitcnt vmcnt(1)" ::: "memory");
        else
            asm volatile("s_waitcnt vmcnt(0)" ::: "memory");
        __builtin_amdgcn_s_barrier();
    }
#undef STG_A
#undef STG_B
#undef AV_PTR
#undef BW_PTR
#undef PHASE_MID
#undef PHASE_END

    // ---- handoff: bias+relu, h -> LDS as [64 cchunk][128 n][8] bf16
    {
        float bv1[8];
#pragma unroll
        for (int ni = 0; ni < 8; ++ni)
            bv1[ni] = B1[128 * wc + 16 * ni + (lane & 15)];
#pragma unroll
        for (int mi = 0; mi < 4; ++mi)
#pragma unroll
            for (int ni = 0; ni < 8; ++ni)
#pragma unroll
                for (int rr = 0; rr < 4; ++rr) {
                    int n = 64 * wr + 16 * mi + (lane >> 4) * 4 + rr;
                    int c = 128 * wc + 16 * ni + (lane & 15);
                    float v = fmaxf(acc1[mi][ni][rr] + bv1[ni], 0.f);
                    LDSu[(c >> 3) * 1024 + n * 8 + (c & 7)] = f2bf(v);
                }
    }
    __syncthreads();

    // ---- stage-2: Out2 = h . W2^T + b2, K=512 in 16 chunks of 32.
    f32x4 acc2[4][2];
#pragma unroll
    for (int mi = 0; mi < 4; ++mi) {
        acc2[mi][0] = (f32x4){0.f, 0.f, 0.f, 0.f};
        acc2[mi][1] = (f32x4){0.f, 0.f, 0.f, 0.f};
    }
    const int c2base = (S2 == L_DIM) ? 32 * wc : 16 * wc;
    const int cA = c2base + (lane & 15);
    const int cB = c2base + 16 + (lane & 15);   // f-path only

    for (int k2 = 0; k2 < 16; ++k2) {
        bf16x8 a2[4];
#pragma unroll
        for (int mi = 0; mi < 4; ++mi)
            a2[mi] = *(const bf16x8*)&LDSu[(k2 * 4 + (lane >> 4)) * 1024 +
                                           (64 * wr + 16 * mi + (lane & 15)) * 8];
        bf16x8 w0 = *(const bf16x8*)(W2 + (size_t)cA * HID + k2 * 32 + (lane >> 4) * 8);
        bf16x8 w1;
        if (S2 == L_DIM)
            w1 = *(const bf16x8*)(W2 + (size_t)cB * HID + k2 * 32 + (lane >> 4) * 8);
#pragma unroll
        for (int mi = 0; mi < 4; ++mi) {
            acc2[mi][0] = __builtin_amdgcn_mfma_f32_16x16x32_bf16(
                a2[mi], w0, acc2[mi][0], 0, 0, 0);
            if (S2 == L_DIM)
                acc2[mi][1] = __builtin_amdgcn_mfma_f32_16x16x32_bf16(
                    a2[mi], w1, acc2[mi][1], 0, 0, 0);
        }
    }

    const float b20 = B2[cA];
    const float b21 = (S2 == L_DIM) ? B2[cB] : 0.f;
    u16* Ob = O2 + (size_t)bz * N_LOC * S2;
#pragma unroll
    for (int mi = 0; mi < 4; ++mi)
#pragma unroll
        for (int rr = 0; rr < 4; ++rr) {
            int row = r0 + 64 * wr + 16 * mi + (lane >> 4) * 4 + rr;
            Ob[(size_t)row * S2 + cA] = f2bf(acc2[mi][0][rr] + b20);
            if (S2 == L_DIM)
                Ob[(size_t)row * S2 + cB] = f2bf(acc2[mi][1][rr] + b21);
        }
}

// ---------------------------------------------------------------------------
// Token MLP stage 1: hidb[b][j] = relu(t[b] . tw1[j] + tb1[j]); grid (8,B).
// ---------------------------------------------------------------------------
__global__ __launch_bounds__(256) void tok1_kernel(const float* __restrict__ t,
                                                   const float* __restrict__ tw1,
                                                   const float* __restrict__ tb1,
                                                   float* __restrict__ hidb) {
    __shared__ __align__(16) float tl[C_IN];
    const int b = blockIdx.y;
    const int j0 = blockIdx.x * 64;
    const int tid = threadIdx.x;
    const int lane = tid & 63;
    const int wave = tid >> 6;
    for (int i = tid; i < C_IN; i += 256) tl[i] = t[(size_t)b * C_IN + i];
    __syncthreads();
    for (int j = wave; j < 64; j += 4) {
        const int row = j0 + j;
        const float4* wr = (const float4*)(tw1 + (size_t)row * C_IN);
        const float4* tr = (const float4*)tl;
        float s = 0.f;
#pragma unroll
        for (int q = 0; q < 3; ++q) {
            float4 wv = wr[lane + 64 * q];
            float4 tv = tr[lane + 64 * q];
            s += wv.x * tv.x + wv.y * tv.y + wv.z * tv.z + wv.w * tv.w;
        }
        s = waveReduceSum(s);
        if (lane == 0) hidb[(size_t)b * HID + row] = fmaxf(s + tb1[row], 0.f);
    }
}

// ---------------------------------------------------------------------------
// Token MLP stage 2: tok[b][g] = hidb[b] . tw2[g] + tb2[g]; grid (4,B).
// ---------------------------------------------------------------------------
__global__ __launch_bounds__(256) void tok2_kernel(const float* __restrict__ hidb,
                                                   const float* __restrict__ tw2,
                                                   const float* __restrict__ tb2,
                                                   float* __restrict__ tok) {
    __shared__ __align__(16) float hl[HID];
    const int b = blockIdx.y;
    const int g0 = blockIdx.x * 64;
    const int tid = threadIdx.x;
    const int lane = tid & 63;
    const int wave = tid >> 6;
    for (int i = tid; i < HID; i += 256) hl[i] = hidb[(size_t)b * HID + i];
    __syncthreads();
    for (int j = wave; j < 64; j += 4) {
        const int row = g0 + j;
        const float4* wr = (const float4*)(tw2 + (size_t)row * HID);
        const float4* hr = (const float4*)hl;
        float s = 0.f;
#pragma unroll
        for (int q = 0; q < 2; ++q) {
            float4 wv = wr[lane + 64 * q];
            float4 hv = hr[lane + 64 * q];
            s += wv.x * hv.x + wv.y * hv.y + wv.z * hv.z + wv.w * hv.w;
        }
        s = waveReduceSum(s);
        if (lane == 0) tok[(size_t)b * G_DIM + row] = s + tb2[row];
    }
}

// ---------------------------------------------------------------------------
// Sinkhorn: pT [B][N][M] bf16 -> PT [B][N][M] fp32. One block/batch.
// ---------------------------------------------------------------------------
__global__ __launch_bounds__(1024) void sinkhorn_kernel(const u16* __restrict__ pT,
                                                        const float* __restrict__ dust,
                                                        float* __restrict__ PT) {
    __shared__ u16 sp[M_DIM][N_LOC];
    __shared__ float u[M_DIM + 1];
    __shared__ float v[N_LOC];
    const int b = blockIdx.x;
    const int t = threadIdx.x;
    const int lane = t & 63;
    const int wave = t >> 6;
    const float alpha = dust[0];
    const float norm = -__logf(1088.f);
    const float logmu_main = norm;
    const float logmu_last = __logf(960.f) + norm;
    const float lognu = norm;

    const uint4* prow = (const uint4*)(pT + ((size_t)b * N_LOC + t) * M_DIM);
#pragma unroll
    for (int q = 0; q < 8; ++q) {
        uint4 ch = prow[q];
        sp[q * 8 + 0][t] = (u16)(ch.x);
        sp[q * 8 + 1][t] = (u16)(ch.x >> 16);
        sp[q * 8 + 2][t] = (u16)(ch.y);
        sp[q * 8 + 3][t] = (u16)(ch.y >> 16);
        sp[q * 8 + 4][t] = (u16)(ch.z);
        sp[q * 8 + 5][t] = (u16)(ch.z >> 16);
        sp[q * 8 + 6][t] = (u16)(ch.w);
        sp[q * 8 + 7][t] = (u16)(ch.w >> 16);
    }
    v[t] = 0.f;
    if (t < M_DIM + 1) u[t] = 0.f;
    __syncthreads();

    for (int it = 0; it < 3; ++it) {
        for (int m = wave; m < M_DIM + 1; m += 16) {
            float s = 0.f;
            if (m < M_DIM) {
#pragma unroll
                for (int q = 0; q < 16; ++q) {
                    int c = lane + 64 * q;
                    s += __expf(bf2f(sp[m][c]) + v[c]);
                }
            } else {
#pragma unroll
                for (int q = 0; q < 16; ++q) {
                    int c = lane + 64 * q;
                    s += __expf(alpha + v[c]);
                }
            }
            s = waveReduceSum(s);
            if (lane == 0) u[m] = ((m < M_DIM) ? logmu_main : logmu_last) - __logf(s);
        }
        __syncthreads();
        float s = 0.f;
#pragma unroll 8
        for (int m = 0; m < M_DIM; ++m) s += __expf(bf2f(sp[m][t]) + u[m]);
        s += __expf(alpha + u[M_DIM]);
        v[t] = lognu - __logf(s);
        __syncthreads();
    }

    const float vt = v[t];
    float* Prow = PT + ((size_t)b * N_LOC + t) * M_DIM;
#pragma unroll
    for (int m4 = 0; m4 < M_DIM; m4 += 4) {
        float4 o;
        o.x = __expf(bf2f(sp[m4 + 0][t]) + u[m4 + 0] + vt - norm);
        o.y = __expf(bf2f(sp[m4 + 1][t]) + u[m4 + 1] + vt - norm);
        o.z = __expf(bf2f(sp[m4 + 2][t]) + u[m4 + 2] + vt - norm);
        o.w = __expf(bf2f(sp[m4 + 3][t]) + u[m4 + 3] + vt - norm);
        *(float4*)(Prow + m4) = o;
    }
}

// ---------------------------------------------------------------------------
// agg[b,l,m] = sum_n fT[b,n,l] * PT[b,n,m]. grid (4,B), 256 thr.
// ---------------------------------------------------------------------------
__global__ __launch_bounds__(256) void agg_kernel(const u16* __restrict__ fT,
                                                  const float* __restrict__ PT,
                                                  float* __restrict__ agg) {
    __shared__ float Fs[64][36];
    __shared__ float Ps[64][68];
    const int b = blockIdx.y;
    const int l0 = blockIdx.x * 32;
    const int tid = threadIdx.x;
    const u16* fb = fT + (size_t)b * N_LOC * L_DIM;
    const float* Pb = PT + (size_t)b * N_LOC * M_DIM;

    const int sn = tid >> 2;
    const int flc = (tid & 3) * 8;
    const int pmc = (tid & 3) * 16;
    const int tl = (tid >> 4) * 2;
    const int tm = (tid & 15) * 4;

    float acc[2][4] = {};

    for (int n0 = 0; n0 < N_LOC; n0 += 64) {
        __syncthreads();
        {
            uint4 ld = *(const uint4*)(fb + (size_t)(n0 + sn) * L_DIM + l0 + flc);
            Fs[sn][flc + 0] = bf2f((u16)(ld.x));
            Fs[sn][flc + 1] = bf2f((u16)(ld.x >> 16));
            Fs[sn][flc + 2] = bf2f((u16)(ld.y));
            Fs[sn][flc + 3] = bf2f((u16)(ld.y >> 16));
            Fs[sn][flc + 4] = bf2f((u16)(ld.z));
            Fs[sn][flc + 5] = bf2f((u16)(ld.z >> 16));
            Fs[sn][flc + 6] = bf2f((u16)(ld.w));
            Fs[sn][flc + 7] = bf2f((u16)(ld.w >> 16));
        }
#pragma unroll
        for (int i = 0; i < 4; ++i) {
            float4 vv = *(const float4*)(Pb + (size_t)(n0 + sn) * M_DIM + pmc + 4 * i);
            *(float4*)&Ps[sn][pmc + 4 * i] = vv;
        }
        __syncthreads();
#pragma unroll 8
        for (int nn = 0; nn < 64; ++nn) {
            float a0 = Fs[nn][tl];
            float a1 = Fs[nn][tl + 1];
            float4 p4 = *(const float4*)&Ps[nn][tm];
            acc[0][0] = fmaf(a0, p4.x, acc[0][0]);
            acc[0][1] = fmaf(a0, p4.y, acc[0][1]);
            acc[0][2] = fmaf(a0, p4.z, acc[0][2]);
            acc[0][3] = fmaf(a0, p4.w, acc[0][3]);
            acc[1][0] = fmaf(a1, p4.x, acc[1][0]);
            acc[1][1] = fmaf(a1, p4.y, acc[1][1]);
            acc[1][2] = fmaf(a1, p4.z, acc[1][2]);
            acc[1][3] = fmaf(a1, p4.w, acc[1][3]);
        }
    }

#pragma unroll
    for (int i = 0; i < 2; ++i) {
        float* dst = agg + ((size_t)b * L_DIM + l0 + tl + i) * M_DIM + tm;
        *(float4*)dst = make_float4(acc[i][0], acc[i][1], acc[i][2], acc[i][3]);
    }
}

// ---------------------------------------------------------------------------
// Final normalization cascade.
// ---------------------------------------------------------------------------
__global__ __launch_bounds__(256) void final_kernel(const float* __restrict__ agg,
                                                    const float* __restrict__ tok,
                                                    float* __restrict__ out) {
    __shared__ __align__(16) float ag[L_DIM * M_DIM];
    __shared__ float rm[M_DIM];
    __shared__ float red[4];
    __shared__ float tk[G_DIM];
    const int b = blockIdx.x;
    const int tid = threadIdx.x;
    const int lane = tid & 63;
    const int wave = tid >> 6;
    const float EPS = 1e-12f;

    const float4* ab = (const float4*)(agg + (size_t)b * L_DIM * M_DIM);
    for (int e4 = tid; e4 < L_DIM * M_DIM / 4; e4 += 256) ((float4*)ag)[e4] = ab[e4];
    tk[tid] = tok[(size_t)b * G_DIM + tid];
    __syncthreads();

    if (tid < M_DIM) {
        float ss = 0.f;
#pragma unroll 8
        for (int l = 0; l < L_DIM; ++l) {
            float x = ag[l * M_DIM + tid];
            ss = fmaf(x, x, ss);
        }
        rm[tid] = 1.f / fmaxf(sqrtf(ss), EPS);
    }
    const float tv = tk[tid];
    float ssl = tv * tv;
    ssl = waveReduceSum(ssl);
    if (lane == 0) red[wave] = ssl;
    __syncthreads();
    const float stok = red[0] + red[1] + red[2] + red[3];
    const float rt = 1.f / fmaxf(sqrtf(stok), EPS);
    const float tn = tv * rt;

    float gs = tn * tn;
    for (int e = tid; e < L_DIM * M_DIM; e += 256) {
        float x = ag[e] * rm[e & (M_DIM - 1)];
        gs = fmaf(x, x, gs);
    }
    __syncthreads();
    gs = waveReduceSum(gs);
    if (lane == 0) red[wave] = gs;
    __syncthreads();
    const float G = red[0] + red[1] + red[2] + red[3];
    const float rg = 1.f / fmaxf(sqrtf(G), EPS);

    float* ob = out + (size_t)b * (G_DIM + L_DIM * M_DIM);
    ob[tid] = tn * rg;
    for (int e = tid; e < L_DIM * M_DIM; e += 256)
        ob[G_DIM + e] = ag[e] * rm[e & (M_DIM - 1)] * rg;
}

// ---------------------------------------------------------------------------
extern "C" void kernel_launch(void* const* d_in, const int* in_sizes, int n_in,
                              void* d_out, int out_size, void* d_ws, size_t ws_size,
                              hipStream_t stream) {
    const float* x    = (const float*)d_in[0];
    const float* t    = (const float*)d_in[1];
    const float* tw1  = (const float*)d_in[2];
    const float* tb1  = (const float*)d_in[3];
    const float* tw2  = (const float*)d_in[4];
    const float* tb2  = (const float*)d_in[5];
    const float* cw1  = (const float*)d_in[6];
    const float* cb1  = (const float*)d_in[7];
    const float* cw2  = (const float*)d_in[8];
    const float* cb2  = (const float*)d_in[9];
    const float* sw1  = (const float*)d_in[10];
    const float* sb1  = (const float*)d_in[11];
    const float* sw2  = (const float*)d_in[12];
    const float* sb2  = (const float*)d_in[13];
    const float* dust = (const float*)d_in[14];
    float* out = (float*)d_out;

    char* ws = (char*)d_ws;
    u16* xT    = (u16*)(ws);                         // 100,663,296
    u16* fT    = (u16*)(ws + 100663296ull);          //  16,777,216
    u16* pT    = (u16*)(ws + 117440512ull);          //   8,388,608
    u16* cw1b  = (u16*)(ws + 125829120ull);          //     786,432
    u16* sw1b  = (u16*)(ws + 126615552ull);          //     786,432
    u16* cw2b  = (u16*)(ws + 127401984ull);          //     131,072
    u16* sw2b  = (u16*)(ws + 127533056ull);          //      65,536
    float* hidb = (float*)(ws + 127598592ull);       //     131,072
    // reuse of dead xT region after fused12:
    float* PT     = (float*)(ws);                    //  16,777,216
    float* tokbuf = (float*)(ws + 20971520ull);      //      65,536
    float* aggbuf = (float*)(ws + 25165824ull);      //   2,097,152

    convert_all<<<864, 256, 0, stream>>>(cw1, sw1, cw2, sw2, cw1b, sw1b, cw2b, sw2b);
    transpose_x<<<dim3(N_LOC / 64, C_IN / 64, B_SZ), 256, 0, stream>>>(x, xT);

    fused12<<<dim3(8, 2, B_SZ), 512, 0, stream>>>(
        xT, cw1b, cb1, cw2b, cb2, sw1b, sb1, sw2b, sb2, fT, pT);

    tok1_kernel<<<dim3(HID / 64, B_SZ), 256, 0, stream>>>(t, tw1, tb1, hidb);
    tok2_kernel<<<dim3(G_DIM / 64, B_SZ), 256, 0, stream>>>(hidb, tw2, tb2, tokbuf);

    sinkhorn_kernel<<<B_SZ, 1024, 0, stream>>>(pT, dust, PT);
    agg_kernel<<<dim3(L_DIM / 32, B_SZ), 256, 0, stream>>>(fT, PT, aggbuf);
    final_kernel<<<B_SZ, 256, 0, stream>>>(aggbuf, tokbuf, out);
}

// Round 8
// 285.971 us; speedup vs baseline: 1.3137x; 1.2256x over previous
//
#include <hip/hip_runtime.h>
#include <math.h>

// ---------------------------------------------------------------------------
// SALAD forward, round 8: fused stage-1+2 GEMM with PRE-PACKED staging
// layouts. W1 packed to the per-K-tile LDS image [kt][kc][c][8]; x transposed
// directly into the A-tile LDS image [nblk][kt][kc][n][8]; W2 packed into
// MFMA fragment order [k2][kc][c][8]. Every global_load_lds source is
// contiguous (1 KB per wave-instr). Schedule identical to round 7
// (2-phase counted-vmcnt, 16 MFMA/phase). Stage-2 W2 loads 1-deep prefetched.
// B=64, C=768, N=1024, HID=512, L=128, M=64, G=256.
// ---------------------------------------------------------------------------

#define B_SZ   64
#define C_IN   768
#define N_LOC  1024
#define HID    512
#define L_DIM  128
#define M_DIM  64
#define G_DIM  256

typedef unsigned short u16;
typedef __bf16 bf16x8 __attribute__((ext_vector_type(8)));
typedef float f32x4 __attribute__((ext_vector_type(4)));

typedef const __attribute__((address_space(1))) void* gptr_t;
typedef __attribute__((address_space(3))) void* sptr_t;

__device__ __forceinline__ void load_lds16(const void* g, void* l) {
    __builtin_amdgcn_global_load_lds((gptr_t)g, (sptr_t)l, 16, 0, 0);
}

__device__ __forceinline__ u16 f2bf(float f) {  // round-to-nearest-even
    unsigned u = __float_as_uint(f);
    u += 0x7fffu + ((u >> 16) & 1u);
    return (u16)(u >> 16);
}
__device__ __forceinline__ float bf2f(u16 h) {
    return __uint_as_float(((unsigned)h) << 16);
}

__device__ __forceinline__ float waveReduceSum(float v) {
#pragma unroll
    for (int off = 32; off > 0; off >>= 1) v += __shfl_xor(v, off, 64);
    return v;
}

// ---------------------------------------------------------------------------
// Weight prep (one launch, 432 blocks x 256 thr; one 8-elem chunk/thread).
//  q in [0, 98304): W1 pack, [path][kt 24][kc 4][c 512][8],
//                   chunk src = W1[c][kt*32 + kc*8 .. +8].
//  q in [98304, 110592): W2 pack, [path][k2 16][kc 4][c S2][8],
//                   chunk src = W2[c][k2*32 + kc*8 .. +8].  (S2: f=128, p=64)
// Packed chunks are written consecutively => staging loads fully contiguous.
// ---------------------------------------------------------------------------
__global__ __launch_bounds__(256) void prep_weights(
        const float* __restrict__ cw1, const float* __restrict__ sw1,
        const float* __restrict__ cw2, const float* __restrict__ sw2,
        u16* __restrict__ cw1p, u16* __restrict__ sw1p,
        u16* __restrict__ cw2p, u16* __restrict__ sw2p) {
    const int q = blockIdx.x * 256 + threadIdx.x;
    const float* src;
    u16* dst;
    if (q < 98304) {                       // W1: 2 x 24 x 4 x 512 chunks
        int path = q / 49152, r = q % 49152;
        int kt = r / 2048, kc = (r / 512) & 3, c = r & 511;
        src = (path ? sw1 : cw1) + (size_t)c * C_IN + kt * 32 + kc * 8;
        dst = (path ? sw1p : cw1p) + (size_t)r * 8;
    } else {                               // W2: f 8192 + p 4096 chunks
        int q2 = q - 98304;
        int path = (q2 >= 8192) ? 1 : 0;
        int r = q2 - (path ? 8192 : 0);
        int S2 = path ? M_DIM : L_DIM;
        int k2 = r / (4 * S2), kc = (r / S2) & 3, c = r % S2;
        src = (path ? sw2 : cw2) + (size_t)c * HID + k2 * 32 + kc * 8;
        dst = (path ? sw2p : cw2p) + (size_t)r * 8;
    }
    float4 v0 = *(const float4*)(src);
    float4 v1 = *(const float4*)(src + 4);
    *(ushort4*)(dst) = make_ushort4(f2bf(v0.x), f2bf(v0.y), f2bf(v0.z), f2bf(v0.w));
    *(ushort4*)(dst + 4) = make_ushort4(f2bf(v1.x), f2bf(v1.y), f2bf(v1.z), f2bf(v1.w));
}

// ---------------------------------------------------------------------------
// x [B][C][N] fp32 -> xPack bf16 in A-tile LDS image order:
//   addr(b,n,c) = b*N*C + (n>>7)*(128*C) + (c>>5)*4096 + ((c&31)>>3)*1024
//                 + (n&127)*8 + (c&7)
// 64x64 tiles via LDS; writes are 16B/lane contiguous (1KB per wave).
// grid = (N/64, C/64, B), block 256.
// ---------------------------------------------------------------------------
__global__ __launch_bounds__(256) void transpose_x(const float* __restrict__ x,
                                                   u16* __restrict__ xP) {
    __shared__ float tile[64][65];
    const int n0 = blockIdx.x * 64;
    const int c0 = blockIdx.y * 64;
    const size_t b = blockIdx.z;
    const float* xb = x + b * (size_t)(C_IN * N_LOC);
    u16* xpb = xP + b * (size_t)(N_LOC * C_IN);
    const int tid = threadIdx.x;

    // load: 64 c-rows x 64 n, float4 per lane (coalesced)
    const int jn = (tid & 15) * 4;
    const int cr = tid >> 4;
#pragma unroll
    for (int r = 0; r < 4; ++r) {
        int c = cr + r * 16;
        float4 v = *(const float4*)(xb + (size_t)(c0 + c) * N_LOC + n0 + jn);
        tile[c][jn + 0] = v.x;
        tile[c][jn + 1] = v.y;
        tile[c][jn + 2] = v.z;
        tile[c][jn + 3] = v.w;
    }
    __syncthreads();

    // write: thread owns (n = tid&63, chunk ch and ch+4); 8 consecutive c.
    const int n = tid & 63;
    const int ch0 = tid >> 6;        // 0..3
    const int nG = n0 + n;
#pragma unroll
    for (int r = 0; r < 2; ++r) {
        const int ch = ch0 + r * 4;          // 0..7
        const int cG = c0 + ch * 8;
        u16* dst = xpb + (size_t)(nG >> 7) * (128 * C_IN) + (cG >> 5) * 4096 +
                   ((cG & 31) >> 3) * 1024 + (nG & 127) * 8;
        ushort4 o0 = make_ushort4(f2bf(tile[ch * 8 + 0][n]), f2bf(tile[ch * 8 + 1][n]),
                                  f2bf(tile[ch * 8 + 2][n]), f2bf(tile[ch * 8 + 3][n]));
        ushort4 o1 = make_ushort4(f2bf(tile[ch * 8 + 4][n]), f2bf(tile[ch * 8 + 5][n]),
                                  f2bf(tile[ch * 8 + 6][n]), f2bf(tile[ch * 8 + 7][n]));
        *(ushort4*)(dst) = o0;
        *(ushort4*)(dst + 4) = o1;
    }
}

// ---------------------------------------------------------------------------
// Fused stage-1 + stage-2 (round-7 schedule, packed staging).
// Stage-1: h[128 n][512 c] = relu(x . W1^T + b1), BK=32, nk=24.
//   8 waves (2 row-halves x 4 col-quarters), acc1[4][8].
//   LDS: A[2][4096 u16] at 0 (image [kc][n][8]);
//        B[2][16384 u16] at 8192 (image [kc][c][8]). 80 KiB live.
//   STG: contiguous pack + tid*8 -> lds + tid*8 (1 KB/wave-instr).
//   tile t: ph0 {read av+bwl | STG_B(t+1)->db^1 | MFMA ni 0..3}
//           ph1 {read bwh    | STG_A(t+2)->db   | MFMA ni 4..7}
//           boundary vmcnt(1) (A(t+2) in flight), barrier.
// Handoff: h -> LDS [64 cchunk][128 n][8] (128 KiB union), syncthreads.
// Stage-2: Out2 = h . W2^T + b2, K=512; W2 fragments from packed global
//   (coalesced), 1-deep register prefetch; no barriers.
// grid (8, 2, 64) XCD-bijective remap; 512 threads.
// ---------------------------------------------------------------------------
__global__ __launch_bounds__(512, 2) void fused12(
        const u16* __restrict__ xP,
        const u16* __restrict__ cw1p, const float* __restrict__ cb1,
        const u16* __restrict__ cw2p, const float* __restrict__ cb2,
        const u16* __restrict__ sw1p, const float* __restrict__ sb1,
        const u16* __restrict__ sw2p, const float* __restrict__ sb2,
        u16* __restrict__ fT, u16* __restrict__ pT) {
    __shared__ __align__(16) u16 LDSu[65536];   // 128 KiB union
    const int tid = threadIdx.x;
    const int lane = tid & 63;
    const int wid = tid >> 6;
    const int wr = wid >> 2;   // 0..1 : row half (64 rows)
    const int wc = wid & 3;    // 0..3 : col quarter (128 cols)

    const int id = blockIdx.x + 8 * blockIdx.y + 16 * blockIdx.z;
    const int nid = (id & 7) * 128 + (id >> 3);   // 1024 % 8 == 0, bijective
    const int bx = nid & 7;
    const int path = (nid >> 3) & 1;
    const int bz = nid >> 4;
    const int r0 = bx * 128;

    const u16* W1p = path ? sw1p : cw1p;
    const float* B1 = path ? sb1 : cb1;
    const u16* W2p = path ? sw2p : cw2p;
    const float* B2 = path ? sb2 : cb2;
    u16* O2 = path ? pT : fT;
    const int S2 = path ? M_DIM : L_DIM;

    // A pack base for this (batch, row-block): 24 tiles x 4096 u16
    const u16* Ap = xP + (size_t)bz * N_LOC * C_IN + (size_t)bx * (128 * C_IN);

    f32x4 acc1[4][8];
#pragma unroll
    for (int mi = 0; mi < 4; ++mi)
#pragma unroll
        for (int ni = 0; ni < 8; ++ni)
            acc1[mi][ni] = (f32x4){0.f, 0.f, 0.f, 0.f};

    const int nk = C_IN / 32;   // 24

#define STG_A(db_, kt_)                                                        \
    load_lds16(Ap + (size_t)(kt_) * 4096 + tid * 8, &LDSu[(db_) * 4096 + tid * 8])
#define STG_B(db_, kt_)                                                        \
    do {                                                                       \
        _Pragma("unroll")                                                      \
        for (int j_ = 0; j_ < 4; ++j_)                                         \
            load_lds16(W1p + (size_t)(kt_) * 16384 + (size_t)(j_ * 512 + tid) * 8, \
                       &LDSu[8192 + (db_) * 16384 + (j_ * 512 + tid) * 8]);    \
    } while (0)

#define AV_PTR(db_, mi_)                                                       \
    ((const bf16x8*)&LDSu[(db_) * 4096 + (lane >> 4) * 1024 +                  \
                          (64 * wr + 16 * (mi_) + (lane & 15)) * 8])
#define BW_PTR(db_, ni_)                                                       \
    ((const bf16x8*)&LDSu[8192 + (db_) * 16384 + (lane >> 4) * 4096 +          \
                          (128 * wc + 16 * (ni_) + (lane & 15)) * 8])

#define PHASE_MID()                                                            \
    __builtin_amdgcn_s_barrier();                                              \
    asm volatile("s_waitcnt lgkmcnt(0)" ::: "memory");                         \
    __builtin_amdgcn_sched_barrier(0);                                         \
    __builtin_amdgcn_s_setprio(1)

#define PHASE_END()                                                            \
    __builtin_amdgcn_s_setprio(0);                                             \
    __builtin_amdgcn_sched_barrier(0);                                         \
    __builtin_amdgcn_s_barrier()

    // prologue: tile0 (A+B), tile1 A. vmcnt(1): tile0 landed, A(1) in flight.
    STG_A(0, 0);
    STG_B(0, 0);
    STG_A(1, 1);
    asm volatile("s_waitcnt vmcnt(1)" ::: "memory");
    __builtin_amdgcn_s_barrier();

    for (int t = 0; t < nk; ++t) {
        const int db = t & 1;
        bf16x8 av[4], bwl[4], bwh[4];

        // ---- phase 0 : cols ni 0..3
#pragma unroll
        for (int mi = 0; mi < 4; ++mi) av[mi] = *AV_PTR(db, mi);
#pragma unroll
        for (int ni = 0; ni < 4; ++ni) bwl[ni] = *BW_PTR(db, ni);
        if (t + 1 < nk) STG_B(db ^ 1, t + 1);
        PHASE_MID();
#pragma unroll
        for (int mi = 0; mi < 4; ++mi)
#pragma unroll
            for (int ni = 0; ni < 4; ++ni)
                acc1[mi][ni] = __builtin_amdgcn_mfma_f32_16x16x32_bf16(
                    av[mi], bwl[ni], acc1[mi][ni], 0, 0, 0);
        PHASE_END();

        // ---- phase 1 : cols ni 4..7 (av reused from registers)
#pragma unroll
        for (int ni = 0; ni < 4; ++ni) bwh[ni] = *BW_PTR(db, 4 + ni);
        if (t + 2 < nk) STG_A(db, t + 2);
        PHASE_MID();
#pragma unroll
        for (int mi = 0; mi < 4; ++mi)
#pragma unroll
            for (int ni = 0; ni < 4; ++ni)
                acc1[mi][4 + ni] = __builtin_amdgcn_mfma_f32_16x16x32_bf16(
                    av[mi], bwh[ni], acc1[mi][4 + ni], 0, 0, 0);
        __builtin_amdgcn_s_setprio(0);
        __builtin_amdgcn_sched_barrier(0);
        if (t + 2 < nk)
            asm volatile("s_waitcnt vmcnt(1)" ::: "memory");
        else
            asm volatile("s_waitcnt vmcnt(0)" ::: "memory");
        __builtin_amdgcn_s_barrier();
    }
#undef STG_A
#undef STG_B
#undef AV_PTR
#undef BW_PTR
#undef PHASE_MID
#undef PHASE_END

    // ---- handoff: bias+relu, h -> LDS as [64 cchunk][128 n][8] bf16
    {
        float bv1[8];
#pragma unroll
        for (int ni = 0; ni < 8; ++ni)
            bv1[ni] = B1[128 * wc + 16 * ni + (lane & 15)];
#pragma unroll
        for (int mi = 0; mi < 4; ++mi)
#pragma unroll
            for (int ni = 0; ni < 8; ++ni)
#pragma unroll
                for (int rr = 0; rr < 4; ++rr) {
                    int n = 64 * wr + 16 * mi + (lane >> 4) * 4 + rr;
                    int c = 128 * wc + 16 * ni + (lane & 15);
                    float v = fmaxf(acc1[mi][ni][rr] + bv1[ni], 0.f);
                    LDSu[(c >> 3) * 1024 + n * 8 + (c & 7)] = f2bf(v);
                }
    }
    __syncthreads();

    // ---- stage-2: Out2 = h . W2^T + b2, K=512 in 16 chunks of 32.
    f32x4 acc2[4][2];
#pragma unroll
    for (int mi = 0; mi < 4; ++mi) {
        acc2[mi][0] = (f32x4){0.f, 0.f, 0.f, 0.f};
        acc2[mi][1] = (f32x4){0.f, 0.f, 0.f, 0.f};
    }
    const int c2base = (S2 == L_DIM) ? 32 * wc : 16 * wc;
    const int cA = c2base + (lane & 15);
    const int cB = c2base + 16 + (lane & 15);   // f-path only
    const int fb0 = (lane >> 4) * S2 + cA;      // packed fragment index
    const int fb1 = (lane >> 4) * S2 + cB;

    bf16x8 w0n = *(const bf16x8*)(W2p + (size_t)fb0 * 8);
    bf16x8 w1n = {};
    if (S2 == L_DIM) w1n = *(const bf16x8*)(W2p + (size_t)fb1 * 8);

    for (int k2 = 0; k2 < 16; ++k2) {
        bf16x8 w0 = w0n, w1 = w1n;
        if (k2 < 15) {
            w0n = *(const bf16x8*)(W2p + ((size_t)(k2 + 1) * 4 * S2 + fb0) * 8);
            if (S2 == L_DIM)
                w1n = *(const bf16x8*)(W2p + ((size_t)(k2 + 1) * 4 * S2 + fb1) * 8);
        }
        bf16x8 a2[4];
#pragma unroll
        for (int mi = 0; mi < 4; ++mi)
            a2[mi] = *(const bf16x8*)&LDSu[(k2 * 4 + (lane >> 4)) * 1024 +
                                           (64 * wr + 16 * mi + (lane & 15)) * 8];
#pragma unroll
        for (int mi = 0; mi < 4; ++mi) {
            acc2[mi][0] = __builtin_amdgcn_mfma_f32_16x16x32_bf16(
                a2[mi], w0, acc2[mi][0], 0, 0, 0);
            if (S2 == L_DIM)
                acc2[mi][1] = __builtin_amdgcn_mfma_f32_16x16x32_bf16(
                    a2[mi], w1, acc2[mi][1], 0, 0, 0);
        }
    }

    const float b20 = B2[cA];
    const float b21 = (S2 == L_DIM) ? B2[cB] : 0.f;
    u16* Ob = O2 + (size_t)bz * N_LOC * S2;
#pragma unroll
    for (int mi = 0; mi < 4; ++mi)
#pragma unroll
        for (int rr = 0; rr < 4; ++rr) {
            int row = r0 + 64 * wr + 16 * mi + (lane >> 4) * 4 + rr;
            Ob[(size_t)row * S2 + cA] = f2bf(acc2[mi][0][rr] + b20);
            if (S2 == L_DIM)
                Ob[(size_t)row * S2 + cB] = f2bf(acc2[mi][1][rr] + b21);
        }
}

// ---------------------------------------------------------------------------
// Token MLP stage 1: hidb[b][j] = relu(t[b] . tw1[j] + tb1[j]); grid (8,B).
// ---------------------------------------------------------------------------
__global__ __launch_bounds__(256) void tok1_kernel(const float* __restrict__ t,
                                                   const float* __restrict__ tw1,
                                                   const float* __restrict__ tb1,
                                                   float* __restrict__ hidb) {
    __shared__ __align__(16) float tl[C_IN];
    const int b = blockIdx.y;
    const int j0 = blockIdx.x * 64;
    const int tid = threadIdx.x;
    const int lane = tid & 63;
    const int wave = tid >> 6;
    for (int i = tid; i < C_IN; i += 256) tl[i] = t[(size_t)b * C_IN + i];
    __syncthreads();
    for (int j = wave; j < 64; j += 4) {
        const int row = j0 + j;
        const float4* wr = (const float4*)(tw1 + (size_t)row * C_IN);
        const float4* tr = (const float4*)tl;
        float s = 0.f;
#pragma unroll
        for (int q = 0; q < 3; ++q) {
            float4 wv = wr[lane + 64 * q];
            float4 tv = tr[lane + 64 * q];
            s += wv.x * tv.x + wv.y * tv.y + wv.z * tv.z + wv.w * tv.w;
        }
        s = waveReduceSum(s);
        if (lane == 0) hidb[(size_t)b * HID + row] = fmaxf(s + tb1[row], 0.f);
    }
}

// ---------------------------------------------------------------------------
// Token MLP stage 2: tok[b][g] = hidb[b] . tw2[g] + tb2[g]; grid (4,B).
// ---------------------------------------------------------------------------
__global__ __launch_bounds__(256) void tok2_kernel(const float* __restrict__ hidb,
                                                   const float* __restrict__ tw2,
                                                   const float* __restrict__ tb2,
                                                   float* __restrict__ tok) {
    __shared__ __align__(16) float hl[HID];
    const int b = blockIdx.y;
    const int g0 = blockIdx.x * 64;
    const int tid = threadIdx.x;
    const int lane = tid & 63;
    const int wave = tid >> 6;
    for (int i = tid; i < HID; i += 256) hl[i] = hidb[(size_t)b * HID + i];
    __syncthreads();
    for (int j = wave; j < 64; j += 4) {
        const int row = g0 + j;
        const float4* wr = (const float4*)(tw2 + (size_t)row * HID);
        const float4* hr = (const float4*)hl;
        float s = 0.f;
#pragma unroll
        for (int q = 0; q < 2; ++q) {
            float4 wv = wr[lane + 64 * q];
            float4 hv = hr[lane + 64 * q];
            s += wv.x * hv.x + wv.y * hv.y + wv.z * hv.z + wv.w * hv.w;
        }
        s = waveReduceSum(s);
        if (lane == 0) tok[(size_t)b * G_DIM + row] = s + tb2[row];
    }
}

// ---------------------------------------------------------------------------
// Sinkhorn: pT [B][N][M] bf16 -> PT [B][N][M] fp32. One block/batch.
// ---------------------------------------------------------------------------
__global__ __launch_bounds__(1024) void sinkhorn_kernel(const u16* __restrict__ pT,
                                                        const float* __restrict__ dust,
                                                        float* __restrict__ PT) {
    __shared__ u16 sp[M_DIM][N_LOC];
    __shared__ float u[M_DIM + 1];
    __shared__ float v[N_LOC];
    const int b = blockIdx.x;
    const int t = threadIdx.x;
    const int lane = t & 63;
    const int wave = t >> 6;
    const float alpha = dust[0];
    const float norm = -__logf(1088.f);
    const float logmu_main = norm;
    const float logmu_last = __logf(960.f) + norm;
    const float lognu = norm;

    const uint4* prow = (const uint4*)(pT + ((size_t)b * N_LOC + t) * M_DIM);
#pragma unroll
    for (int q = 0; q < 8; ++q) {
        uint4 ch = prow[q];
        sp[q * 8 + 0][t] = (u16)(ch.x);
        sp[q * 8 + 1][t] = (u16)(ch.x >> 16);
        sp[q * 8 + 2][t] = (u16)(ch.y);
        sp[q * 8 + 3][t] = (u16)(ch.y >> 16);
        sp[q * 8 + 4][t] = (u16)(ch.z);
        sp[q * 8 + 5][t] = (u16)(ch.z >> 16);
        sp[q * 8 + 6][t] = (u16)(ch.w);
        sp[q * 8 + 7][t] = (u16)(ch.w >> 16);
    }
    v[t] = 0.f;
    if (t < M_DIM + 1) u[t] = 0.f;
    __syncthreads();

    for (int it = 0; it < 3; ++it) {
        for (int m = wave; m < M_DIM + 1; m += 16) {
            float s = 0.f;
            if (m < M_DIM) {
#pragma unroll
                for (int q = 0; q < 16; ++q) {
                    int c = lane + 64 * q;
                    s += __expf(bf2f(sp[m][c]) + v[c]);
                }
            } else {
#pragma unroll
                for (int q = 0; q < 16; ++q) {
                    int c = lane + 64 * q;
                    s += __expf(alpha + v[c]);
                }
            }
            s = waveReduceSum(s);
            if (lane == 0) u[m] = ((m < M_DIM) ? logmu_main : logmu_last) - __logf(s);
        }
        __syncthreads();
        float s = 0.f;
#pragma unroll 8
        for (int m = 0; m < M_DIM; ++m) s += __expf(bf2f(sp[m][t]) + u[m]);
        s += __expf(alpha + u[M_DIM]);
        v[t] = lognu - __logf(s);
        __syncthreads();
    }

    const float vt = v[t];
    float* Prow = PT + ((size_t)b * N_LOC + t) * M_DIM;
#pragma unroll
    for (int m4 = 0; m4 < M_DIM; m4 += 4) {
        float4 o;
        o.x = __expf(bf2f(sp[m4 + 0][t]) + u[m4 + 0] + vt - norm);
        o.y = __expf(bf2f(sp[m4 + 1][t]) + u[m4 + 1] + vt - norm);
        o.z = __expf(bf2f(sp[m4 + 2][t]) + u[m4 + 2] + vt - norm);
        o.w = __expf(bf2f(sp[m4 + 3][t]) + u[m4 + 3] + vt - norm);
        *(float4*)(Prow + m4) = o;
    }
}

// ---------------------------------------------------------------------------
// agg[b,l,m] = sum_n fT[b,n,l] * PT[b,n,m]. grid (4,B), 256 thr.
// ---------------------------------------------------------------------------
__global__ __launch_bounds__(256) void agg_kernel(const u16* __restrict__ fT,
                                                  const float* __restrict__ PT,
                                                  float* __restrict__ agg) {
    __shared__ float Fs[64][36];
    __shared__ float Ps[64][68];
    const int b = blockIdx.y;
    const int l0 = blockIdx.x * 32;
    const int tid = threadIdx.x;
    const u16* fb = fT + (size_t)b * N_LOC * L_DIM;
    const float* Pb = PT + (size_t)b * N_LOC * M_DIM;

    const int sn = tid >> 2;
    const int flc = (tid & 3) * 8;
    const int pmc = (tid & 3) * 16;
    const int tl = (tid >> 4) * 2;
    const int tm = (tid & 15) * 4;

    float acc[2][4] = {};

    for (int n0 = 0; n0 < N_LOC; n0 += 64) {
        __syncthreads();
        {
            uint4 ld = *(const uint4*)(fb + (size_t)(n0 + sn) * L_DIM + l0 + flc);
            Fs[sn][flc + 0] = bf2f((u16)(ld.x));
            Fs[sn][flc + 1] = bf2f((u16)(ld.x >> 16));
            Fs[sn][flc + 2] = bf2f((u16)(ld.y));
            Fs[sn][flc + 3] = bf2f((u16)(ld.y >> 16));
            Fs[sn][flc + 4] = bf2f((u16)(ld.z));
            Fs[sn][flc + 5] = bf2f((u16)(ld.z >> 16));
            Fs[sn][flc + 6] = bf2f((u16)(ld.w));
            Fs[sn][flc + 7] = bf2f((u16)(ld.w >> 16));
        }
#pragma unroll
        for (int i = 0; i < 4; ++i) {
            float4 vv = *(const float4*)(Pb + (size_t)(n0 + sn) * M_DIM + pmc + 4 * i);
            *(float4*)&Ps[sn][pmc + 4 * i] = vv;
        }
        __syncthreads();
#pragma unroll 8
        for (int nn = 0; nn < 64; ++nn) {
            float a0 = Fs[nn][tl];
            float a1 = Fs[nn][tl + 1];
            float4 p4 = *(const float4*)&Ps[nn][tm];
            acc[0][0] = fmaf(a0, p4.x, acc[0][0]);
            acc[0][1] = fmaf(a0, p4.y, acc[0][1]);
            acc[0][2] = fmaf(a0, p4.z, acc[0][2]);
            acc[0][3] = fmaf(a0, p4.w, acc[0][3]);
            acc[1][0] = fmaf(a1, p4.x, acc[1][0]);
            acc[1][1] = fmaf(a1, p4.y, acc[1][1]);
            acc[1][2] = fmaf(a1, p4.z, acc[1][2]);
            acc[1][3] = fmaf(a1, p4.w, acc[1][3]);
        }
    }

#pragma unroll
    for (int i = 0; i < 2; ++i) {
        float* dst = agg + ((size_t)b * L_DIM + l0 + tl + i) * M_DIM + tm;
        *(float4*)dst = make_float4(acc[i][0], acc[i][1], acc[i][2], acc[i][3]);
    }
}

// ---------------------------------------------------------------------------
// Final normalization cascade.
// ---------------------------------------------------------------------------
__global__ __launch_bounds__(256) void final_kernel(const float* __restrict__ agg,
                                                    const float* __restrict__ tok,
                                                    float* __restrict__ out) {
    __shared__ __align__(16) float ag[L_DIM * M_DIM];
    __shared__ float rm[M_DIM];
    __shared__ float red[4];
    __shared__ float tk[G_DIM];
    const int b = blockIdx.x;
    const int tid = threadIdx.x;
    const int lane = tid & 63;
    const int wave = tid >> 6;
    const float EPS = 1e-12f;

    const float4* ab = (const float4*)(agg + (size_t)b * L_DIM * M_DIM);
    for (int e4 = tid; e4 < L_DIM * M_DIM / 4; e4 += 256) ((float4*)ag)[e4] = ab[e4];
    tk[tid] = tok[(size_t)b * G_DIM + tid];
    __syncthreads();

    if (tid < M_DIM) {
        float ss = 0.f;
#pragma unroll 8
        for (int l = 0; l < L_DIM; ++l) {
            float x = ag[l * M_DIM + tid];
            ss = fmaf(x, x, ss);
        }
        rm[tid] = 1.f / fmaxf(sqrtf(ss), EPS);
    }
    const float tv = tk[tid];
    float ssl = tv * tv;
    ssl = waveReduceSum(ssl);
    if (lane == 0) red[wave] = ssl;
    __syncthreads();
    const float stok = red[0] + red[1] + red[2] + red[3];
    const float rt = 1.f / fmaxf(sqrtf(stok), EPS);
    const float tn = tv * rt;

    float gs = tn * tn;
    for (int e = tid; e < L_DIM * M_DIM; e += 256) {
        float x = ag[e] * rm[e & (M_DIM - 1)];
        gs = fmaf(x, x, gs);
    }
    __syncthreads();
    gs = waveReduceSum(gs);
    if (lane == 0) red[wave] = gs;
    __syncthreads();
    const float G = red[0] + red[1] + red[2] + red[3];
    const float rg = 1.f / fmaxf(sqrtf(G), EPS);

    float* ob = out + (size_t)b * (G_DIM + L_DIM * M_DIM);
    ob[tid] = tn * rg;
    for (int e = tid; e < L_DIM * M_DIM; e += 256)
        ob[G_DIM + e] = ag[e] * rm[e & (M_DIM - 1)] * rg;
}

// ---------------------------------------------------------------------------
extern "C" void kernel_launch(void* const* d_in, const int* in_sizes, int n_in,
                              void* d_out, int out_size, void* d_ws, size_t ws_size,
                              hipStream_t stream) {
    const float* x    = (const float*)d_in[0];
    const float* t    = (const float*)d_in[1];
    const float* tw1  = (const float*)d_in[2];
    const float* tb1  = (const float*)d_in[3];
    const float* tw2  = (const float*)d_in[4];
    const float* tb2  = (const float*)d_in[5];
    const float* cw1  = (const float*)d_in[6];
    const float* cb1  = (const float*)d_in[7];
    const float* cw2  = (const float*)d_in[8];
    const float* cb2  = (const float*)d_in[9];
    const float* sw1  = (const float*)d_in[10];
    const float* sb1  = (const float*)d_in[11];
    const float* sw2  = (const float*)d_in[12];
    const float* sb2  = (const float*)d_in[13];
    const float* dust = (const float*)d_in[14];
    float* out = (float*)d_out;

    char* ws = (char*)d_ws;
    u16* xP    = (u16*)(ws);                         // 100,663,296
    u16* fT    = (u16*)(ws + 100663296ull);          //  16,777,216
    u16* pT    = (u16*)(ws + 117440512ull);          //   8,388,608
    u16* cw1p  = (u16*)(ws + 125829120ull);          //     786,432
    u16* sw1p  = (u16*)(ws + 126615552ull);          //     786,432
    u16* cw2p  = (u16*)(ws + 127401984ull);          //     131,072
    u16* sw2p  = (u16*)(ws + 127533056ull);          //      65,536
    float* hidb = (float*)(ws + 127598592ull);       //     131,072
    // reuse of dead xP region after fused12:
    float* PT     = (float*)(ws);                    //  16,777,216
    float* tokbuf = (float*)(ws + 20971520ull);      //      65,536
    float* aggbuf = (float*)(ws + 25165824ull);      //   2,097,152

    prep_weights<<<432, 256, 0, stream>>>(cw1, sw1, cw2, sw2,
                                          cw1p, sw1p, cw2p, sw2p);
    transpose_x<<<dim3(N_LOC / 64, C_IN / 64, B_SZ), 256, 0, stream>>>(x, xP);

    fused12<<<dim3(8, 2, B_SZ), 512, 0, stream>>>(
        xP, cw1p, cb1, cw2p, cb2, sw1p, sb1, sw2p, sb2, fT, pT);

    tok1_kernel<<<dim3(HID / 64, B_SZ), 256, 0, stream>>>(t, tw1, tb1, hidb);
    tok2_kernel<<<dim3(G_DIM / 64, B_SZ), 256, 0, stream>>>(hidb, tw2, tb2, tokbuf);

    sinkhorn_kernel<<<B_SZ, 1024, 0, stream>>>(pT, dust, PT);
    agg_kernel<<<dim3(L_DIM / 32, B_SZ), 256, 0, stream>>>(fT, PT, aggbuf);
    final_kernel<<<B_SZ, 256, 0, stream>>>(aggbuf, tokbuf, out);
}